// Round 6
// baseline (204.974 us; speedup 1.0000x reference)
//
#include <hip/hip_runtime.h>
#include <cstdint>

// Problem constants
constexpr int kN   = 4;
constexpr int kC   = 256;
constexpr int kS   = 2304;   // 48*48
constexpr int kDK  = 256;
constexpr int kDV  = 256;
constexpr int kDH  = 32;     // head dim
constexpr int kO   = 768;    // 2*DK + DV

typedef __bf16    bf16x8 __attribute__((ext_vector_type(8)));
typedef float     f32x4  __attribute__((ext_vector_type(4)));
typedef _Float16  f16;
typedef _Float16  f16x4  __attribute__((ext_vector_type(4)));
typedef _Float16  f16x8  __attribute__((ext_vector_type(8)));

union U4  { uint4 u; bf16x8 v; unsigned short s[8]; };
union F4  { float4 f; float a[4]; };
union UF8 { uint4 u; f16x8 v; f16 h[8]; };
union UF4 { uint2 u; f16x4 v; ushort4 su; };

#if __has_builtin(__builtin_amdgcn_exp2f)
#define EXP2(x) __builtin_amdgcn_exp2f(x)
#else
#define EXP2(x) exp2f(x)
#endif

__device__ inline float bf2f(unsigned short h) {
    unsigned int u = ((unsigned int)h) << 16;
    return __builtin_bit_cast(float, u);
}
__device__ inline unsigned short f2bf(float f) {
    unsigned int u = __builtin_bit_cast(unsigned int, f);
    u += 0x7fff + ((u >> 16) & 1);   // RNE
    return (unsigned short)(u >> 16);
}
__device__ inline void split2(float v, unsigned short& h, unsigned short& l) {
    h = f2bf(v);
    l = f2bf(v - bf2f(h));
}
__device__ inline unsigned int pk2(float a, float b) {
    auto p = __builtin_amdgcn_cvt_pkrtz(a, b);
    return __builtin_bit_cast(unsigned int, p);
}

// Fragment layouts (16x16x32 MFMA, verified m89/m120 algebra):
//   A/B-frag elem (row, k): lane = ((k>>3)&3)*16 + (row&15), j = k&7
//   stored as [tile_row][ktile][lane 64][8], each fragment 512 elems contiguous.
//   C-layout: D[row = (lane>>4)*4 + reg][col = lane&15].

// ---------------------------------------------------------------------------
// prep_x: x[n][c][s] fp32 -> split-bf16 A-fragment order
//   xh/xl [n][stile 144][ktile 8][lane][8]   (row = s, k = c)
// Block: 256 thr handles 64 s x 32 c. Grid (36, 8, 4).
// ---------------------------------------------------------------------------
__global__ __launch_bounds__(256) void prep_x(const float* __restrict__ x,
                                              unsigned short* __restrict__ xh,
                                              unsigned short* __restrict__ xl) {
    __shared__ float t[32][65];
    int n    = blockIdx.z;
    int cblk = blockIdx.y;     // c tile of 32
    int sblk = blockIdx.x;     // s tile of 64
    int tid  = threadIdx.x;

    const float* xb = x + (size_t)n * kC * kS + (size_t)cblk * 32 * kS + (size_t)sblk * 64;
    {   // read 32c x 64s
        int cr = tid >> 3, sg = (tid & 7) * 8;
        F4 a0, a1;
        a0.f = *(const float4*)(xb + (size_t)cr * kS + sg);
        a1.f = *(const float4*)(xb + (size_t)cr * kS + sg + 4);
#pragma unroll
        for (int j = 0; j < 4; j++) t[cr][sg + j] = a0.a[j];
#pragma unroll
        for (int j = 0; j < 4; j++) t[cr][sg + 4 + j] = a1.a[j];
    }
    __syncthreads();
    {
        int s_loc = tid & 63, cg = tid >> 6;        // cg: 8-c group (0..3)
        int s_g   = sblk * 64 + s_loc;
        U4 hv, lv;
#pragma unroll
        for (int j = 0; j < 8; j++) split2(t[cg * 8 + j][s_loc], hv.s[j], lv.s[j]);
        size_t frag = ((size_t)(n * 144 + (s_g >> 4)) * 8 + cblk) * 512
                      + (cg * 16 + (s_g & 15)) * 8;
        *(uint4*)(xh + frag) = hv.u;
        *(uint4*)(xl + frag) = lv.u;
    }
}

// ---------------------------------------------------------------------------
// prep_w: w_qkv fp32 -> split-bf16 B-fragment order wh/wl [otile 48][ktile 8][lane][8]
//         w_proj fp32 -> f16 A-fragment order wp [otile 16][ktile 8][lane][8]
// Grid 128 x 256.
// ---------------------------------------------------------------------------
__global__ __launch_bounds__(256) void prep_w(const float* __restrict__ w_qkv,
                                              const float* __restrict__ w_proj,
                                              unsigned short* __restrict__ wh,
                                              unsigned short* __restrict__ wl,
                                              f16* __restrict__ wp) {
    int idx = blockIdx.x * 256 + threadIdx.x;
    if (idx < 24576) {           // w_qkv: 768 o x 32 c-groups
        int o = idx >> 5, cg = idx & 31;
        F4 a0, a1;
        a0.f = *(const float4*)(w_qkv + (size_t)o * kC + cg * 8);
        a1.f = *(const float4*)(w_qkv + (size_t)o * kC + cg * 8 + 4);
        U4 hv, lv;
#pragma unroll
        for (int j = 0; j < 4; j++) split2(a0.a[j], hv.s[j], lv.s[j]);
#pragma unroll
        for (int j = 0; j < 4; j++) split2(a1.a[j], hv.s[j + 4], lv.s[j + 4]);
        size_t frag = ((size_t)(o >> 4) * 8 + (cg >> 2)) * 512 + ((cg & 3) * 16 + (o & 15)) * 8;
        *(uint4*)(wh + frag) = hv.u;
        *(uint4*)(wl + frag) = lv.u;
    } else {                     // w_proj: 256 o x 32 dv-groups
        int i2 = idx - 24576;
        int o = i2 >> 5, cg = i2 & 31;
        F4 a0, a1;
        a0.f = *(const float4*)(w_proj + (size_t)o * kDV + cg * 8);
        a1.f = *(const float4*)(w_proj + (size_t)o * kDV + cg * 8 + 4);
        UF8 w;
#pragma unroll
        for (int j = 0; j < 4; j++) w.h[j] = (f16)a0.a[j];
#pragma unroll
        for (int j = 0; j < 4; j++) w.h[j + 4] = (f16)a1.a[j];
        size_t frag = ((size_t)(o >> 4) * 8 + (cg >> 2)) * 512 + ((cg & 3) * 16 + (o & 15)) * 8;
        *(uint4*)(wp + frag) = w.u;
    }
}

// ---------------------------------------------------------------------------
// gemm_qkv: LDS-free, barrier-free. qkv[s][o] = x[s][:]·w[o][:] + b, split-bf16
// (3 MFMAs). Single wave computes 64s x 64o (4x4 frags), K=256 in 8 ktiles,
// double-buffered fragment loads. Grid (12 o, 36 s, 4 n), block 64.
// Epilogue -> Qf/Kf row-major [nh][s][32] (Q prescaled DK^-0.5/ln2),
// Vp in PV A-fragment order [nh][tb 144][dt 2][lane][4].
// ---------------------------------------------------------------------------
__global__ __launch_bounds__(64) void gemm_qkv(const unsigned short* __restrict__ xh,
                                               const unsigned short* __restrict__ xl,
                                               const unsigned short* __restrict__ wh,
                                               const unsigned short* __restrict__ wl,
                                               const float* __restrict__ bias,
                                               f16* __restrict__ Qf,
                                               f16* __restrict__ Kf,
                                               f16* __restrict__ Vp) {
    int ob = blockIdx.x, sb = blockIdx.y, n = blockIdx.z;
    int lane = threadIdx.x;
    int l15  = lane & 15;
    int quad = lane >> 4;

    const unsigned short* ahb = xh + ((size_t)(n * 144 + sb * 4) * 8) * 512 + (size_t)lane * 8;
    const unsigned short* alb = xl + ((size_t)(n * 144 + sb * 4) * 8) * 512 + (size_t)lane * 8;
    const unsigned short* bhb = wh + ((size_t)(ob * 4) * 8) * 512 + (size_t)lane * 8;
    const unsigned short* blb = wl + ((size_t)(ob * 4) * 8) * 512 + (size_t)lane * 8;

    bf16x8 Ah[2][4], Al[2][4], Bh[2][4], Bl[2][4];
    auto ld = [&](int kt, int b) {
#pragma unroll
        for (int i = 0; i < 4; i++) {
            U4 u;
            u.u = *(const uint4*)(ahb + (i * 8 + kt) * 512); Ah[b][i] = u.v;
            u.u = *(const uint4*)(alb + (i * 8 + kt) * 512); Al[b][i] = u.v;
            u.u = *(const uint4*)(bhb + (i * 8 + kt) * 512); Bh[b][i] = u.v;
            u.u = *(const uint4*)(blb + (i * 8 + kt) * 512); Bl[b][i] = u.v;
        }
    };

    f32x4 acc[4][4] = {};
    ld(0, 0);
#pragma unroll
    for (int kt = 0; kt < 8; kt++) {
        int cur = kt & 1;
        if (kt < 7) ld(kt + 1, cur ^ 1);
#pragma unroll
        for (int mt = 0; mt < 4; mt++)
#pragma unroll
            for (int nt = 0; nt < 4; nt++) {
                acc[mt][nt] = __builtin_amdgcn_mfma_f32_16x16x32_bf16(Ah[cur][mt], Bh[cur][nt], acc[mt][nt], 0, 0, 0);
                acc[mt][nt] = __builtin_amdgcn_mfma_f32_16x16x32_bf16(Ah[cur][mt], Bl[cur][nt], acc[mt][nt], 0, 0, 0);
                acc[mt][nt] = __builtin_amdgcn_mfma_f32_16x16x32_bf16(Al[cur][mt], Bh[cur][nt], acc[mt][nt], 0, 0, 0);
            }
    }

    // Epilogue: D[row=s][col=o], row = quad*4+r, col = l15.
    constexpr float kQScale = 0.0625f * 1.4426950408889634f;
#pragma unroll
    for (int nt = 0; nt < 4; nt++) {
        int col = ob * 64 + nt * 16 + l15;
        float bcol = bias[col];
        int sec = col >> 8;          // 0=K, 1=Q, 2=V
        int h   = (col >> 5) & 7;
        int d   = col & 31;
        int nh  = n * 8 + h;
#pragma unroll
        for (int mt = 0; mt < 4; mt++) {
            int row0 = sb * 64 + mt * 16 + quad * 4;
            if (sec == 2) {
                UF4 w;
#pragma unroll
                for (int r = 0; r < 4; r++) w.v[r] = (f16)(acc[mt][nt][r] + bcol);
                int dt = (col >> 4) & 1;
                size_t off = ((((size_t)nh * 144 + (row0 >> 4)) * 2 + dt) * 64 + lane) * 4;
                *(ushort4*)(Vp + off) = w.su;
            } else if (sec == 0) {
#pragma unroll
                for (int r = 0; r < 4; r++)
                    Kf[((size_t)nh * kS + row0 + r) * kDH + d] = (f16)(acc[mt][nt][r] + bcol);
            } else {
#pragma unroll
                for (int r = 0; r < 4; r++)
                    Qf[((size_t)nh * kS + row0 + r) * kDH + d] =
                        (f16)((acc[mt][nt][r] + bcol) * kQScale);
            }
        }
    }
}

// ---------------------------------------------------------------------------
// attn: LDS-free, barrier-free, triple-buffered prefetch (distance 2).
// One wave, 32 q-rows. S^T = K·Q^T (16x16x32), exp2 in-register, P feeds PV
// (16x16x16, A=V^T frags) directly. Epilogue writes attnF in gemm_out
// B-fragment order. Grid (72, 8, 4), block 64.
// ---------------------------------------------------------------------------
__global__ __launch_bounds__(64) void attn_f16(const f16* __restrict__ Qf,
                                               const f16* __restrict__ Kf,
                                               const f16* __restrict__ Vp,
                                               f16* __restrict__ attnF) {
    int qw = blockIdx.x, h = blockIdx.y, n = blockIdx.z;
    int nh = n * 8 + h;
    int lane = threadIdx.x;
    int l15  = lane & 15;
    int quad = lane >> 4;
    int sqb  = qw * 32;

    const f16* Qb = Qf + (size_t)nh * kS * kDH;
    const f16* kp = Kf + (size_t)nh * kS * kDH + l15 * kDH + quad * 8;
    const f16* vp = Vp + (size_t)nh * 144 * 512 + lane * 4;

    f16x8 qf[2];
    {
        UF8 u;
        u.u = *(const uint4*)(Qb + (size_t)(sqb + l15) * kDH + quad * 8);      qf[0] = u.v;
        u.u = *(const uint4*)(Qb + (size_t)(sqb + 16 + l15) * kDH + quad * 8); qf[1] = u.v;
    }

    f32x4 oacc[2][2] = {};     // [dt][sqf]: O^T[d=dt*16+quad*4+r][sq=sqf*16+l15]
    float lsum[2] = {0.f, 0.f};

    f16x8 kf[3][4];
    f16x4 vf[3][4][2];
    auto ldK = [&](int t, int b) {
#pragma unroll
        for (int tt = 0; tt < 4; tt++) {
            UF8 u; u.u = *(const uint4*)(kp + (size_t)t * 2048 + tt * 512);
            kf[b][tt] = u.v;
        }
    };
    auto ldV = [&](int t, int b) {
#pragma unroll
        for (int kk = 0; kk < 4; kk++)
#pragma unroll
            for (int dt = 0; dt < 2; dt++) {
                UF4 u; u.u = *(const uint2*)(vp + (size_t)t * 2048 + kk * 512 + dt * 256);
                vf[b][kk][dt] = u.v;
            }
    };
    auto step = [&](int b) {
        f16x4 pf[2][4];
#pragma unroll
        for (int sqf = 0; sqf < 2; sqf++)
#pragma unroll
            for (int tt = 0; tt < 4; tt++) {
                f32x4 z = {};
                z = __builtin_amdgcn_mfma_f32_16x16x32_f16(kf[b][tt], qf[sqf], z, 0, 0, 0);
                float e0 = EXP2(z[0]), e1 = EXP2(z[1]);
                float e2 = EXP2(z[2]), e3 = EXP2(z[3]);
                lsum[sqf] += (e0 + e1) + (e2 + e3);
                UF4 w;
                w.u.x = pk2(e0, e1);
                w.u.y = pk2(e2, e3);
                pf[sqf][tt] = w.v;
            }
#pragma unroll
        for (int kk = 0; kk < 4; kk++)
#pragma unroll
            for (int dt = 0; dt < 2; dt++)
#pragma unroll
                for (int sqf = 0; sqf < 2; sqf++)
                    oacc[dt][sqf] = __builtin_amdgcn_mfma_f32_16x16x16f16(
                        vf[b][kk][dt], pf[sqf][kk], oacc[dt][sqf], 0, 0, 0);
    };

    ldK(0, 0); ldV(0, 0);
    ldK(1, 1); ldV(1, 1);
    for (int it = 0; it < 36; it += 3) {     // 36 t-tiles of 64
        ldK(it + 2, 2); ldV(it + 2, 2); step(0);   // over-reads at tail land in
        ldK(it + 3, 0); ldV(it + 3, 0); step(1);   // adjacent ws buffers (unused)
        ldK(it + 4, 1); ldV(it + 4, 1); step(2);
    }

#pragma unroll
    for (int sqf = 0; sqf < 2; sqf++) {
        float v = lsum[sqf];
        v += __shfl_xor(v, 16);
        v += __shfl_xor(v, 32);
        lsum[sqf] = v;
    }

    // epilogue: normalize, write attnF B-fragment order:
    //   elem (s, dv): ktile = h, lane' = ((dv&31)>>3)*16 + (s&15), j = dv&7
    // our lane holds dv_local = dt*16+quad*4+r, s = sqf*16+l15 -> one 8B store.
#pragma unroll
    for (int sqf = 0; sqf < 2; sqf++) {
        float inv = 1.0f / lsum[sqf];
        int stile = qw * 2 + sqf;
#pragma unroll
        for (int dt = 0; dt < 2; dt++) {
            UF4 w;
#pragma unroll
            for (int r = 0; r < 4; r++) w.v[r] = (f16)(oacc[dt][sqf][r] * inv);
            size_t off = (((size_t)(n * 144 + stile) * 8 + h) * 512)
                         + ((dt * 2 + (quad >> 1)) * 16 + l15) * 8 + (quad & 1) * 4;
            *(uint2*)(attnF + off) = w.u;
        }
    }
}

// ---------------------------------------------------------------------------
// gemm_out: LDS-free, barrier-free. out[n][o][s] = w_proj[o][:]·attn[s][:]+b.
// Single wave 64o x 64s, K=256 in 8 ktiles, double-buffered. Grid (4,36,4).
// ---------------------------------------------------------------------------
__global__ __launch_bounds__(64) void gemm_out(const f16* __restrict__ wp,
                                               const f16* __restrict__ attnF,
                                               const float* __restrict__ bias,
                                               float* __restrict__ out) {
    int ob = blockIdx.x, sb = blockIdx.y, n = blockIdx.z;
    int lane = threadIdx.x;
    int l15  = lane & 15;
    int quad = lane >> 4;

    const f16* ap = wp + ((size_t)(ob * 4) * 8) * 512 + (size_t)lane * 8;
    const f16* bp = attnF + ((size_t)(n * 144 + sb * 4) * 8) * 512 + (size_t)lane * 8;

    f16x8 af[2][4], bf[2][4];
    auto ld = [&](int kt, int b) {
#pragma unroll
        for (int i = 0; i < 4; i++) {
            UF8 u;
            u.u = *(const uint4*)(ap + (i * 8 + kt) * 512); af[b][i] = u.v;
            u.u = *(const uint4*)(bp + (i * 8 + kt) * 512); bf[b][i] = u.v;
        }
    };

    f32x4 acc[4][4] = {};
    ld(0, 0);
#pragma unroll
    for (int kt = 0; kt < 8; kt++) {
        int cur = kt & 1;
        if (kt < 7) ld(kt + 1, cur ^ 1);
#pragma unroll
        for (int mt = 0; mt < 4; mt++)
#pragma unroll
            for (int nt = 0; nt < 4; nt++)
                acc[mt][nt] = __builtin_amdgcn_mfma_f32_16x16x32_f16(af[cur][mt], bf[cur][nt],
                                                                     acc[mt][nt], 0, 0, 0);
    }

#pragma unroll
    for (int mt = 0; mt < 4; mt++) {
        int row0 = ob * 64 + mt * 16 + quad * 4;   // o
#pragma unroll
        for (int nt = 0; nt < 4; nt++) {
            int col = sb * 64 + nt * 16 + l15;     // s
#pragma unroll
            for (int r = 0; r < 4; r++)
                out[((size_t)n * kDV + row0 + r) * kS + col] = acc[mt][nt][r] + bias[row0 + r];
        }
    }
}

// ---------------------------------------------------------------------------
extern "C" void kernel_launch(void* const* d_in, const int* in_sizes, int n_in,
                              void* d_out, int out_size, void* d_ws, size_t ws_size,
                              hipStream_t stream) {
    const float* x      = (const float*)d_in[0];
    const float* w_qkv  = (const float*)d_in[1];
    const float* b_qkv  = (const float*)d_in[2];
    const float* w_proj = (const float*)d_in[3];
    const float* b_proj = (const float*)d_in[4];
    float* out = (float*)d_out;

    constexpr size_t kXE = (size_t)kN * kS * kC;     // 2,359,296
    unsigned short* xh = (unsigned short*)d_ws;      // A-frag bf16 hi
    unsigned short* xl = xh + kXE;                   // A-frag bf16 lo
    unsigned short* wh = xl + kXE;                   // w_qkv B-frag hi (196608)
    unsigned short* wl = wh + 196608;
    f16* wpF   = (f16*)(wl + 196608);                // w_proj A-frag f16 (65536)
    f16* Qf    = wpF + 65536;                        // [32 nh][2304][32]
    f16* Kf    = Qf + kXE;
    f16* Vp    = Kf + kXE;                           // [32 nh][144][2][64][4]
    f16* attnF = Vp + kXE;                           // B-frag [n][144][8][512]

    prep_x<<<dim3(36, 8, 4), 256, 0, stream>>>(x, xh, xl);
    prep_w<<<dim3(128), 256, 0, stream>>>(w_qkv, w_proj, wh, wl, wpF);

    gemm_qkv<<<dim3(12, 36, 4), 64, 0, stream>>>(xh, xl, wh, wl, b_qkv, Qf, Kf, Vp);

    attn_f16<<<dim3(72, 8, 4), 64, 0, stream>>>(Qf, Kf, Vp, attnF);

    gemm_out<<<dim3(4, 36, 4), 64, 0, stream>>>(wpF, attnF, b_proj, out);
}

// Round 7
// 162.947 us; speedup vs baseline: 1.2579x; 1.2579x over previous
//
#include <hip/hip_runtime.h>
#include <cstdint>

// Problem constants
constexpr int kN   = 4;
constexpr int kC   = 256;
constexpr int kS   = 2304;   // 48*48
constexpr int kDK  = 256;
constexpr int kDV  = 256;
constexpr int kDH  = 32;     // head dim
constexpr int kO   = 768;    // 2*DK + DV

typedef __bf16    bf16x8 __attribute__((ext_vector_type(8)));
typedef float     f32x4  __attribute__((ext_vector_type(4)));
typedef _Float16  f16;
typedef _Float16  f16x4  __attribute__((ext_vector_type(4)));
typedef _Float16  f16x8  __attribute__((ext_vector_type(8)));

union U4  { uint4 u; bf16x8 v; unsigned short s[8]; };
union F4  { float4 f; float a[4]; };
union UF8 { uint4 u; f16x8 v; f16 h[8]; };
union UF4 { uint2 u; f16x4 v; ushort4 su; };

#if __has_builtin(__builtin_amdgcn_exp2f)
#define EXP2(x) __builtin_amdgcn_exp2f(x)
#else
#define EXP2(x) exp2f(x)
#endif

__device__ inline float bf2f(unsigned short h) {
    unsigned int u = ((unsigned int)h) << 16;
    return __builtin_bit_cast(float, u);
}
__device__ inline unsigned short f2bf(float f) {
    unsigned int u = __builtin_bit_cast(unsigned int, f);
    u += 0x7fff + ((u >> 16) & 1);   // RNE
    return (unsigned short)(u >> 16);
}
__device__ inline void split2(float v, unsigned short& h, unsigned short& l) {
    h = f2bf(v);
    l = f2bf(v - bf2f(h));
}
__device__ inline unsigned int pk2(float a, float b) {
    auto p = __builtin_amdgcn_cvt_pkrtz(a, b);
    return __builtin_bit_cast(unsigned int, p);
}

// Fragment layouts (16x16x32 MFMA, correctness-verified in round 6):
//   A/B-frag elem (row, k): lane = ((k>>3)&3)*16 + (row&15), j = k&7
//   stored [tile_row][ktile][lane 64][8]; each fragment = 512 elems contiguous.
//   C-layout: D[row = (lane>>4)*4 + reg][col = lane&15].

// ---------------------------------------------------------------------------
// prep_x: x[n][c][s] fp32 -> split-bf16 A-fragment order
//   xh/xl [n][stile 144][ktile 8][lane][8]   (row = s, k = c)
// ---------------------------------------------------------------------------
__global__ __launch_bounds__(256) void prep_x(const float* __restrict__ x,
                                              unsigned short* __restrict__ xh,
                                              unsigned short* __restrict__ xl) {
    __shared__ float t[32][65];
    int n    = blockIdx.z;
    int cblk = blockIdx.y;     // c tile of 32
    int sblk = blockIdx.x;     // s tile of 64
    int tid  = threadIdx.x;

    const float* xb = x + (size_t)n * kC * kS + (size_t)cblk * 32 * kS + (size_t)sblk * 64;
    {
        int cr = tid >> 3, sg = (tid & 7) * 8;
        F4 a0, a1;
        a0.f = *(const float4*)(xb + (size_t)cr * kS + sg);
        a1.f = *(const float4*)(xb + (size_t)cr * kS + sg + 4);
#pragma unroll
        for (int j = 0; j < 4; j++) t[cr][sg + j] = a0.a[j];
#pragma unroll
        for (int j = 0; j < 4; j++) t[cr][sg + 4 + j] = a1.a[j];
    }
    __syncthreads();
    {
        int s_loc = tid & 63, cg = tid >> 6;        // cg: 8-c group (0..3)
        int s_g   = sblk * 64 + s_loc;
        U4 hv, lv;
#pragma unroll
        for (int j = 0; j < 8; j++) split2(t[cg * 8 + j][s_loc], hv.s[j], lv.s[j]);
        size_t frag = ((size_t)(n * 144 + (s_g >> 4)) * 8 + cblk) * 512
                      + (cg * 16 + (s_g & 15)) * 8;
        *(uint4*)(xh + frag) = hv.u;
        *(uint4*)(xl + frag) = lv.u;
    }
}

// ---------------------------------------------------------------------------
// prep_w: w_qkv fp32 -> split-bf16 B-frag order wh/wl [otile 48][ktile 8][lane][8]
//         w_proj fp32 -> f16 A-frag order wp [otile 16][ktile 8][lane][8]
// ---------------------------------------------------------------------------
__global__ __launch_bounds__(256) void prep_w(const float* __restrict__ w_qkv,
                                              const float* __restrict__ w_proj,
                                              unsigned short* __restrict__ wh,
                                              unsigned short* __restrict__ wl,
                                              f16* __restrict__ wp) {
    int idx = blockIdx.x * 256 + threadIdx.x;
    if (idx < 24576) {           // w_qkv: 768 o x 32 c-groups
        int o = idx >> 5, cg = idx & 31;
        F4 a0, a1;
        a0.f = *(const float4*)(w_qkv + (size_t)o * kC + cg * 8);
        a1.f = *(const float4*)(w_qkv + (size_t)o * kC + cg * 8 + 4);
        U4 hv, lv;
#pragma unroll
        for (int j = 0; j < 4; j++) split2(a0.a[j], hv.s[j], lv.s[j]);
#pragma unroll
        for (int j = 0; j < 4; j++) split2(a1.a[j], hv.s[j + 4], lv.s[j + 4]);
        size_t frag = ((size_t)(o >> 4) * 8 + (cg >> 2)) * 512 + ((cg & 3) * 16 + (o & 15)) * 8;
        *(uint4*)(wh + frag) = hv.u;
        *(uint4*)(wl + frag) = lv.u;
    } else {                     // w_proj: 256 o x 32 dv-groups
        int i2 = idx - 24576;
        int o = i2 >> 5, cg = i2 & 31;
        F4 a0, a1;
        a0.f = *(const float4*)(w_proj + (size_t)o * kDV + cg * 8);
        a1.f = *(const float4*)(w_proj + (size_t)o * kDV + cg * 8 + 4);
        UF8 w;
#pragma unroll
        for (int j = 0; j < 4; j++) w.h[j] = (f16)a0.a[j];
#pragma unroll
        for (int j = 0; j < 4; j++) w.h[j + 4] = (f16)a1.a[j];
        size_t frag = ((size_t)(o >> 4) * 8 + (cg >> 2)) * 512 + ((cg & 3) * 16 + (o & 15)) * 8;
        *(uint4*)(wp + frag) = w.u;
    }
}

// ---------------------------------------------------------------------------
// gemm_qkv: LDS-free, barrier-free, fragment-direct, r5-style double buffer.
// Wave computes 64s x 32o (4x2 frags), K=256 in 8 ktiles. Grid (24,36,4).
// Split-bf16: 3 MFMAs per cell. Epilogue -> Qf/Kf [nh][s][32] (Q prescaled),
// Vp PV-A-frag order [nh][tb 144][dt 2][lane][4].
// ---------------------------------------------------------------------------
__global__ __launch_bounds__(64) void gemm_qkv(const unsigned short* __restrict__ xh,
                                               const unsigned short* __restrict__ xl,
                                               const unsigned short* __restrict__ wh,
                                               const unsigned short* __restrict__ wl,
                                               const float* __restrict__ bias,
                                               f16* __restrict__ Qf,
                                               f16* __restrict__ Kf,
                                               f16* __restrict__ Vp) {
    int ob = blockIdx.x, sb = blockIdx.y, n = blockIdx.z;
    int lane = threadIdx.x;
    int l15  = lane & 15;
    int quad = lane >> 4;

    const unsigned short* ah = xh + ((size_t)(n * 144 + sb * 4) * 8) * 512 + (size_t)lane * 8;
    const unsigned short* al = xl + ((size_t)(n * 144 + sb * 4) * 8) * 512 + (size_t)lane * 8;
    const unsigned short* bh = wh + ((size_t)(ob * 2) * 8) * 512 + (size_t)lane * 8;
    const unsigned short* bl = wl + ((size_t)(ob * 2) * 8) * 512 + (size_t)lane * 8;

    bf16x8 Ah[4], Al[4], Bh[2], Bl[2];
    bf16x8 nAh[4], nAl[4], nBh[2], nBl[2];
    {
        U4 u;
#pragma unroll
        for (int i = 0; i < 4; i++) {
            u.u = *(const uint4*)(ah + (i * 8) * 512); Ah[i] = u.v;
            u.u = *(const uint4*)(al + (i * 8) * 512); Al[i] = u.v;
        }
#pragma unroll
        for (int i = 0; i < 2; i++) {
            u.u = *(const uint4*)(bh + (i * 8) * 512); Bh[i] = u.v;
            u.u = *(const uint4*)(bl + (i * 8) * 512); Bl[i] = u.v;
        }
    }

    f32x4 acc[4][2] = {};
#pragma unroll
    for (int kt = 0; kt < 8; kt++) {
        if (kt < 7) {
            U4 u;
#pragma unroll
            for (int i = 0; i < 4; i++) {
                u.u = *(const uint4*)(ah + (i * 8 + kt + 1) * 512); nAh[i] = u.v;
                u.u = *(const uint4*)(al + (i * 8 + kt + 1) * 512); nAl[i] = u.v;
            }
#pragma unroll
            for (int i = 0; i < 2; i++) {
                u.u = *(const uint4*)(bh + (i * 8 + kt + 1) * 512); nBh[i] = u.v;
                u.u = *(const uint4*)(bl + (i * 8 + kt + 1) * 512); nBl[i] = u.v;
            }
        }
#pragma unroll
        for (int mt = 0; mt < 4; mt++)
#pragma unroll
            for (int nt = 0; nt < 2; nt++) {
                acc[mt][nt] = __builtin_amdgcn_mfma_f32_16x16x32_bf16(Ah[mt], Bh[nt], acc[mt][nt], 0, 0, 0);
                acc[mt][nt] = __builtin_amdgcn_mfma_f32_16x16x32_bf16(Ah[mt], Bl[nt], acc[mt][nt], 0, 0, 0);
                acc[mt][nt] = __builtin_amdgcn_mfma_f32_16x16x32_bf16(Al[mt], Bh[nt], acc[mt][nt], 0, 0, 0);
            }
#pragma unroll
        for (int i = 0; i < 4; i++) { Ah[i] = nAh[i]; Al[i] = nAl[i]; }
#pragma unroll
        for (int i = 0; i < 2; i++) { Bh[i] = nBh[i]; Bl[i] = nBl[i]; }
    }

    // Epilogue: D[row=s][col=o], row = quad*4+r, col = l15.
    constexpr float kQScale = 0.0625f * 1.4426950408889634f;
#pragma unroll
    for (int nt = 0; nt < 2; nt++) {
        int col = ob * 32 + nt * 16 + l15;
        float bcol = bias[col];
        int sec = col >> 8;          // 0=K, 1=Q, 2=V
        int h   = (col >> 5) & 7;
        int d   = col & 31;
        int nh  = n * 8 + h;
#pragma unroll
        for (int mt = 0; mt < 4; mt++) {
            int row0 = sb * 64 + mt * 16 + quad * 4;
            if (sec == 2) {
                UF4 w;
#pragma unroll
                for (int r = 0; r < 4; r++) w.v[r] = (f16)(acc[mt][nt][r] + bcol);
                int dt = (col >> 4) & 1;
                size_t off = ((((size_t)nh * 144 + (row0 >> 4)) * 2 + dt) * 64 + lane) * 4;
                *(ushort4*)(Vp + off) = w.su;
            } else if (sec == 0) {
#pragma unroll
                for (int r = 0; r < 4; r++)
                    Kf[((size_t)nh * kS + row0 + r) * kDH + d] = (f16)(acc[mt][nt][r] + bcol);
            } else {
#pragma unroll
                for (int r = 0; r < 4; r++)
                    Qf[((size_t)nh * kS + row0 + r) * kDH + d] =
                        (f16)((acc[mt][nt][r] + bcol) * kQScale);
            }
        }
    }
}

// ---------------------------------------------------------------------------
// attn: exact r5 loop shape (distance-1 prefetch, named cur/next buffers,
// pointer bumps), q-tile 64/wave. S^T = K·Q^T (16x16x32 f16), exp2 in-reg,
// P feeds PV (16x16x16 f16) directly. Epilogue -> attnF in gemm_out B-frag
// order. Grid (36, 8, 4), block 64 -> 1152 waves.
// ---------------------------------------------------------------------------
__global__ __launch_bounds__(64) void attn_f16(const f16* __restrict__ Qf,
                                               const f16* __restrict__ Kf,
                                               const f16* __restrict__ Vp,
                                               f16* __restrict__ attnF) {
    int qw = blockIdx.x, h = blockIdx.y, n = blockIdx.z;
    int nh = n * 8 + h;
    int lane = threadIdx.x;
    int l15  = lane & 15;
    int quad = lane >> 4;
    int sqb  = qw * 64;

    const f16* Qb = Qf + (size_t)nh * kS * kDH;
    const f16* kp = Kf + (size_t)nh * kS * kDH + l15 * kDH + quad * 8;
    const f16* vp = Vp + (size_t)nh * 144 * 512 + lane * 4;

    f16x8 qf[4];
#pragma unroll
    for (int mt = 0; mt < 4; mt++) {
        UF8 u;
        u.u = *(const uint4*)(Qb + (size_t)(sqb + mt * 16 + l15) * kDH + quad * 8);
        qf[mt] = u.v;
    }

    f32x4 oacc[2][4] = {};     // [dt][sqf]: O^T[d=dt*16+quad*4+r][sq=sqf*16+l15]
    float lsum[4] = {0.f, 0.f, 0.f, 0.f};

    f16x8 kfr[4];
    f16x4 vfr[4][2];
#pragma unroll
    for (int tt = 0; tt < 4; tt++) {
        UF8 u; u.u = *(const uint4*)(kp + tt * 512); kfr[tt] = u.v;
    }
#pragma unroll
    for (int kk = 0; kk < 4; kk++)
#pragma unroll
        for (int dt = 0; dt < 2; dt++) {
            UF4 u; u.u = *(const uint2*)(vp + kk * 512 + dt * 256); vfr[kk][dt] = u.v;
        }

    for (int t0 = 0; t0 < kS; t0 += 64) {
        // prefetch next t-tile (final iter over-reads into adjacent ws buffers)
        f16x8 kn[4];
        f16x4 vn[4][2];
#pragma unroll
        for (int tt = 0; tt < 4; tt++) {
            UF8 u; u.u = *(const uint4*)(kp + 2048 + tt * 512); kn[tt] = u.v;
        }
#pragma unroll
        for (int kk = 0; kk < 4; kk++)
#pragma unroll
            for (int dt = 0; dt < 2; dt++) {
                UF4 u; u.u = *(const uint2*)(vp + 2048 + kk * 512 + dt * 256); vn[kk][dt] = u.v;
            }

        // logits (transposed) + exp2 + pack, in-register
        f16x4 pf[4][4];      // pf[sqf][tt]: P^T[t=tt*16+quad*4+r][sq=l15]
#pragma unroll
        for (int sqf = 0; sqf < 4; sqf++)
#pragma unroll
            for (int tt = 0; tt < 4; tt++) {
                f32x4 z = {};
                z = __builtin_amdgcn_mfma_f32_16x16x32_f16(kfr[tt], qf[sqf], z, 0, 0, 0);
                float e0 = EXP2(z[0]), e1 = EXP2(z[1]);
                float e2 = EXP2(z[2]), e3 = EXP2(z[3]);
                lsum[sqf] += (e0 + e1) + (e2 + e3);
                UF4 w;
                w.u.x = pk2(e0, e1);
                w.u.y = pk2(e2, e3);
                pf[sqf][tt] = w.v;
            }

        // PV: O^T += V^T · P^T
#pragma unroll
        for (int kk = 0; kk < 4; kk++)
#pragma unroll
            for (int dt = 0; dt < 2; dt++)
#pragma unroll
                for (int sqf = 0; sqf < 4; sqf++)
                    oacc[dt][sqf] = __builtin_amdgcn_mfma_f32_16x16x16f16(
                        vfr[kk][dt], pf[sqf][kk], oacc[dt][sqf], 0, 0, 0);

#pragma unroll
        for (int tt = 0; tt < 4; tt++) kfr[tt] = kn[tt];
#pragma unroll
        for (int kk = 0; kk < 4; kk++) {
            vfr[kk][0] = vn[kk][0];
            vfr[kk][1] = vn[kk][1];
        }
        kp += 2048;
        vp += 2048;
    }

#pragma unroll
    for (int sqf = 0; sqf < 4; sqf++) {
        float v = lsum[sqf];
        v += __shfl_xor(v, 16);
        v += __shfl_xor(v, 32);
        lsum[sqf] = v;
    }

    // epilogue: normalize; write attnF in gemm_out B-frag order:
    //   our lane holds dv_local = dt*16+quad*4+r, s = sqf*16+l15 -> one 8B store.
#pragma unroll
    for (int sqf = 0; sqf < 4; sqf++) {
        float inv = 1.0f / lsum[sqf];
        int stile = qw * 4 + sqf;
#pragma unroll
        for (int dt = 0; dt < 2; dt++) {
            UF4 w;
#pragma unroll
            for (int r = 0; r < 4; r++) w.v[r] = (f16)(oacc[dt][sqf][r] * inv);
            size_t off = (((size_t)(n * 144 + stile) * 8 + h) * 512)
                         + ((dt * 2 + (quad >> 1)) * 16 + l15) * 8 + (quad & 1) * 4;
            *(uint2*)(attnF + off) = w.u;
        }
    }
}

// ---------------------------------------------------------------------------
// gemm_out: LDS-free, fragment-direct, r5-style double buffer.
// Wave computes 32o x 64s (2x4 frags), K=256 in 8 ktiles. Grid (8,36,4).
// ---------------------------------------------------------------------------
__global__ __launch_bounds__(64) void gemm_out(const f16* __restrict__ wp,
                                               const f16* __restrict__ attnF,
                                               const float* __restrict__ bias,
                                               float* __restrict__ out) {
    int ob = blockIdx.x, sb = blockIdx.y, n = blockIdx.z;
    int lane = threadIdx.x;
    int l15  = lane & 15;
    int quad = lane >> 4;

    const f16* ap = wp + ((size_t)(ob * 2) * 8) * 512 + (size_t)lane * 8;
    const f16* bp = attnF + ((size_t)(n * 144 + sb * 4) * 8) * 512 + (size_t)lane * 8;

    f16x8 af[2], bf[4], naf[2], nbf[4];
    {
        UF8 u;
#pragma unroll
        for (int i = 0; i < 2; i++) { u.u = *(const uint4*)(ap + (i * 8) * 512); af[i] = u.v; }
#pragma unroll
        for (int i = 0; i < 4; i++) { u.u = *(const uint4*)(bp + (i * 8) * 512); bf[i] = u.v; }
    }

    f32x4 acc[2][4] = {};
#pragma unroll
    for (int kt = 0; kt < 8; kt++) {
        if (kt < 7) {
            UF8 u;
#pragma unroll
            for (int i = 0; i < 2; i++) { u.u = *(const uint4*)(ap + (i * 8 + kt + 1) * 512); naf[i] = u.v; }
#pragma unroll
            for (int i = 0; i < 4; i++) { u.u = *(const uint4*)(bp + (i * 8 + kt + 1) * 512); nbf[i] = u.v; }
        }
#pragma unroll
        for (int mt = 0; mt < 2; mt++)
#pragma unroll
            for (int nt = 0; nt < 4; nt++)
                acc[mt][nt] = __builtin_amdgcn_mfma_f32_16x16x32_f16(af[mt], bf[nt],
                                                                     acc[mt][nt], 0, 0, 0);
#pragma unroll
        for (int i = 0; i < 2; i++) af[i] = naf[i];
#pragma unroll
        for (int i = 0; i < 4; i++) bf[i] = nbf[i];
    }

#pragma unroll
    for (int mt = 0; mt < 2; mt++) {
        int row0 = ob * 32 + mt * 16 + quad * 4;   // o
#pragma unroll
        for (int nt = 0; nt < 4; nt++) {
            int col = sb * 64 + nt * 16 + l15;     // s
#pragma unroll
            for (int r = 0; r < 4; r++)
                out[((size_t)n * kDV + row0 + r) * kS + col] = acc[mt][nt][r] + bias[row0 + r];
        }
    }
}

// ---------------------------------------------------------------------------
extern "C" void kernel_launch(void* const* d_in, const int* in_sizes, int n_in,
                              void* d_out, int out_size, void* d_ws, size_t ws_size,
                              hipStream_t stream) {
    const float* x      = (const float*)d_in[0];
    const float* w_qkv  = (const float*)d_in[1];
    const float* b_qkv  = (const float*)d_in[2];
    const float* w_proj = (const float*)d_in[3];
    const float* b_proj = (const float*)d_in[4];
    float* out = (float*)d_out;

    constexpr size_t kXE = (size_t)kN * kS * kC;     // 2,359,296
    unsigned short* xh = (unsigned short*)d_ws;      // A-frag bf16 hi
    unsigned short* xl = xh + kXE;                   // A-frag bf16 lo
    unsigned short* wh = xl + kXE;                   // w_qkv B-frag hi
    unsigned short* wl = wh + 196608;
    f16* wpF   = (f16*)(wl + 196608);                // w_proj A-frag f16
    f16* Qf    = wpF + 65536;                        // [32 nh][2304][32]
    f16* Kf    = Qf + kXE;
    f16* Vp    = Kf + kXE;                           // [32 nh][144][2][64][4]
    f16* attnF = Vp + kXE;                           // B-frag [n][144][8][512]

    prep_x<<<dim3(36, 8, 4), 256, 0, stream>>>(x, xh, xl);
    prep_w<<<dim3(128), 256, 0, stream>>>(w_qkv, w_proj, wh, wl, wpF);

    gemm_qkv<<<dim3(24, 36, 4), 64, 0, stream>>>(xh, xl, wh, wl, b_qkv, Qf, Kf, Vp);

    attn_f16<<<dim3(36, 8, 4), 64, 0, stream>>>(Qf, Kf, Vp, attnF);

    gemm_out<<<dim3(8, 36, 4), 64, 0, stream>>>(wpF, attnF, b_proj, out);
}

// Round 8
// 152.808 us; speedup vs baseline: 1.3414x; 1.0664x over previous
//
#include <hip/hip_runtime.h>
#include <cstdint>

// Problem constants
constexpr int kN   = 4;
constexpr int kC   = 256;
constexpr int kS   = 2304;   // 48*48
constexpr int kDK  = 256;
constexpr int kDV  = 256;
constexpr int kDH  = 32;     // head dim
constexpr int kO   = 768;    // 2*DK + DV

typedef __bf16    bf16x8 __attribute__((ext_vector_type(8)));
typedef float     f32x4  __attribute__((ext_vector_type(4)));
typedef _Float16  f16;
typedef _Float16  f16x4  __attribute__((ext_vector_type(4)));
typedef _Float16  f16x8  __attribute__((ext_vector_type(8)));

union U4  { uint4 u; bf16x8 v; unsigned short s[8]; };
union F4  { float4 f; float a[4]; };
union UF8 { uint4 u; f16x8 v; f16 h[8]; };
union UF4 { uint2 u; f16x4 v; ushort4 su; };

#if __has_builtin(__builtin_amdgcn_exp2f)
#define EXP2(x) __builtin_amdgcn_exp2f(x)
#else
#define EXP2(x) exp2f(x)
#endif

__device__ inline float bf2f(unsigned short h) {
    unsigned int u = ((unsigned int)h) << 16;
    return __builtin_bit_cast(float, u);
}
__device__ inline unsigned short f2bf(float f) {
    unsigned int u = __builtin_bit_cast(unsigned int, f);
    u += 0x7fff + ((u >> 16) & 1);   // RNE
    return (unsigned short)(u >> 16);
}
__device__ inline void split2(float v, unsigned short& h, unsigned short& l) {
    h = f2bf(v);
    l = f2bf(v - bf2f(h));
}
__device__ inline unsigned int pk2(float a, float b) {
    auto p = __builtin_amdgcn_cvt_pkrtz(a, b);
    return __builtin_bit_cast(unsigned int, p);
}

// Fragment layouts (16x16x32 MFMA, correctness-verified rounds 6/7):
//   A/B-frag elem (row, k): lane = ((k>>3)&3)*16 + (row&15), j = k&7
//   stored [tile_row][ktile][lane 64][8]; each fragment = 512 elems contiguous.
//   C-layout: D[row = (lane>>4)*4 + reg][col = lane&15].

// ---------------------------------------------------------------------------
// prep_x: x[n][c][s] fp32 -> split-bf16 A-fragment order
//   xh/xl [n][stile 144][ktile 8][lane][8]   (row = s, k = c)
// ---------------------------------------------------------------------------
__global__ __launch_bounds__(256) void prep_x(const float* __restrict__ x,
                                              unsigned short* __restrict__ xh,
                                              unsigned short* __restrict__ xl) {
    __shared__ float t[32][65];
    int n    = blockIdx.z;
    int cblk = blockIdx.y;     // c tile of 32
    int sblk = blockIdx.x;     // s tile of 64
    int tid  = threadIdx.x;

    const float* xb = x + (size_t)n * kC * kS + (size_t)cblk * 32 * kS + (size_t)sblk * 64;
    {
        int cr = tid >> 3, sg = (tid & 7) * 8;
        F4 a0, a1;
        a0.f = *(const float4*)(xb + (size_t)cr * kS + sg);
        a1.f = *(const float4*)(xb + (size_t)cr * kS + sg + 4);
#pragma unroll
        for (int j = 0; j < 4; j++) t[cr][sg + j] = a0.a[j];
#pragma unroll
        for (int j = 0; j < 4; j++) t[cr][sg + 4 + j] = a1.a[j];
    }
    __syncthreads();
    {
        int s_loc = tid & 63, cg = tid >> 6;        // cg: 8-c group (0..3)
        int s_g   = sblk * 64 + s_loc;
        U4 hv, lv;
#pragma unroll
        for (int j = 0; j < 8; j++) split2(t[cg * 8 + j][s_loc], hv.s[j], lv.s[j]);
        size_t frag = ((size_t)(n * 144 + (s_g >> 4)) * 8 + cblk) * 512
                      + (cg * 16 + (s_g & 15)) * 8;
        *(uint4*)(xh + frag) = hv.u;
        *(uint4*)(xl + frag) = lv.u;
    }
}

// ---------------------------------------------------------------------------
// prep_w: w_qkv fp32 -> split-bf16 B-frag order wh/wl [otile 48][ktile 8][lane][8]
//         w_proj fp32 -> f16 A-frag order wp [otile 16][ktile 8][lane][8]
// ---------------------------------------------------------------------------
__global__ __launch_bounds__(256) void prep_w(const float* __restrict__ w_qkv,
                                              const float* __restrict__ w_proj,
                                              unsigned short* __restrict__ wh,
                                              unsigned short* __restrict__ wl,
                                              f16* __restrict__ wp) {
    int idx = blockIdx.x * 256 + threadIdx.x;
    if (idx < 24576) {           // w_qkv: 768 o x 32 c-groups
        int o = idx >> 5, cg = idx & 31;
        F4 a0, a1;
        a0.f = *(const float4*)(w_qkv + (size_t)o * kC + cg * 8);
        a1.f = *(const float4*)(w_qkv + (size_t)o * kC + cg * 8 + 4);
        U4 hv, lv;
#pragma unroll
        for (int j = 0; j < 4; j++) split2(a0.a[j], hv.s[j], lv.s[j]);
#pragma unroll
        for (int j = 0; j < 4; j++) split2(a1.a[j], hv.s[j + 4], lv.s[j + 4]);
        size_t frag = ((size_t)(o >> 4) * 8 + (cg >> 2)) * 512 + ((cg & 3) * 16 + (o & 15)) * 8;
        *(uint4*)(wh + frag) = hv.u;
        *(uint4*)(wl + frag) = lv.u;
    } else {                     // w_proj: 256 o x 32 dv-groups
        int i2 = idx - 24576;
        int o = i2 >> 5, cg = i2 & 31;
        F4 a0, a1;
        a0.f = *(const float4*)(w_proj + (size_t)o * kDV + cg * 8);
        a1.f = *(const float4*)(w_proj + (size_t)o * kDV + cg * 8 + 4);
        UF8 w;
#pragma unroll
        for (int j = 0; j < 4; j++) w.h[j] = (f16)a0.a[j];
#pragma unroll
        for (int j = 0; j < 4; j++) w.h[j + 4] = (f16)a1.a[j];
        size_t frag = ((size_t)(o >> 4) * 8 + (cg >> 2)) * 512 + ((cg & 3) * 16 + (o & 15)) * 8;
        *(uint4*)(wp + frag) = w.u;
    }
}

// ---------------------------------------------------------------------------
// gemm_qkv: 4 waves/block share the A-tile (hi/lo frags) via LDS; B frags
// direct from global (L2-hot). Block covers 64 s x 128 o; wave = 64s x 32o
// (4x2 frags), K=256 in 8 ktiles, LDS double-buffered, 1 barrier/ktile.
// Grid (6, 36, 4) = 864 blocks = 3456 waves. Split-bf16 (3 MFMAs/cell).
// Epilogue (r7-verified): Qf/Kf [nh][s][32] (Q prescaled), Vp PV-A-frag.
// ---------------------------------------------------------------------------
__global__ __launch_bounds__(256) void gemm_qkv(const unsigned short* __restrict__ xh,
                                                const unsigned short* __restrict__ xl,
                                                const unsigned short* __restrict__ wh,
                                                const unsigned short* __restrict__ wl,
                                                const float* __restrict__ bias,
                                                f16* __restrict__ Qf,
                                                f16* __restrict__ Kf,
                                                f16* __restrict__ Vp) {
    int ob = blockIdx.x, sb = blockIdx.y, n = blockIdx.z;
    int tid  = threadIdx.x;
    int wid  = tid >> 6;
    int lane = tid & 63;
    int l15  = lane & 15;
    int quad = lane >> 4;

    __shared__ unsigned short AH[2][2048];   // [buf][mt 4][lane 64][8]
    __shared__ unsigned short AL[2][2048];

    const unsigned short* ahb = xh + ((size_t)(n * 144 + sb * 4) * 8) * 512;
    const unsigned short* alb = xl + ((size_t)(n * 144 + sb * 4) * 8) * 512;
    const unsigned short* bhb = wh + ((size_t)(ob * 8 + wid * 2) * 8) * 512 + (size_t)lane * 8;
    const unsigned short* blb = wl + ((size_t)(ob * 8 + wid * 2) * 8) * 512 + (size_t)lane * 8;

    int smt = tid >> 6, sln = tid & 63;      // staging: thread -> (frag, lane)
    auto stageA = [&](int kt, int b) {
        *(uint4*)(&AH[b][tid * 8]) = *(const uint4*)(ahb + (size_t)(smt * 8 + kt) * 512 + sln * 8);
        *(uint4*)(&AL[b][tid * 8]) = *(const uint4*)(alb + (size_t)(smt * 8 + kt) * 512 + sln * 8);
    };

    f32x4 acc[4][2] = {};
    stageA(0, 0);
#pragma unroll
    for (int kt = 0; kt < 8; kt++) {
        int cur = kt & 1;
        __syncthreads();
        if (kt < 7) stageA(kt + 1, cur ^ 1);

        bf16x8 Bh[2], Bl[2];
#pragma unroll
        for (int nt = 0; nt < 2; nt++) {
            U4 u;
            u.u = *(const uint4*)(bhb + (size_t)(nt * 8 + kt) * 512); Bh[nt] = u.v;
            u.u = *(const uint4*)(blb + (size_t)(nt * 8 + kt) * 512); Bl[nt] = u.v;
        }
        bf16x8 Ah[4], Al[4];
#pragma unroll
        for (int mt = 0; mt < 4; mt++) {
            U4 u;
            u.u = *(const uint4*)(&AH[cur][mt * 512 + lane * 8]); Ah[mt] = u.v;
            u.u = *(const uint4*)(&AL[cur][mt * 512 + lane * 8]); Al[mt] = u.v;
        }
#pragma unroll
        for (int mt = 0; mt < 4; mt++)
#pragma unroll
            for (int nt = 0; nt < 2; nt++) {
                acc[mt][nt] = __builtin_amdgcn_mfma_f32_16x16x32_bf16(Ah[mt], Bh[nt], acc[mt][nt], 0, 0, 0);
                acc[mt][nt] = __builtin_amdgcn_mfma_f32_16x16x32_bf16(Ah[mt], Bl[nt], acc[mt][nt], 0, 0, 0);
                acc[mt][nt] = __builtin_amdgcn_mfma_f32_16x16x32_bf16(Al[mt], Bh[nt], acc[mt][nt], 0, 0, 0);
            }
    }

    // Epilogue (r7-verified): D[row=s][col=o], row = quad*4+r, col = l15.
    constexpr float kQScale = 0.0625f * 1.4426950408889634f;
#pragma unroll
    for (int nt = 0; nt < 2; nt++) {
        int col = ob * 128 + wid * 32 + nt * 16 + l15;
        float bcol = bias[col];
        int sec = col >> 8;          // 0=K, 1=Q, 2=V
        int h   = (col >> 5) & 7;
        int d   = col & 31;
        int nh  = n * 8 + h;
#pragma unroll
        for (int mt = 0; mt < 4; mt++) {
            int row0 = sb * 64 + mt * 16 + quad * 4;
            if (sec == 2) {
                UF4 w;
#pragma unroll
                for (int r = 0; r < 4; r++) w.v[r] = (f16)(acc[mt][nt][r] + bcol);
                int dt = (col >> 4) & 1;
                size_t off = ((((size_t)nh * 144 + (row0 >> 4)) * 2 + dt) * 64 + lane) * 4;
                *(ushort4*)(Vp + off) = w.su;
            } else if (sec == 0) {
#pragma unroll
                for (int r = 0; r < 4; r++)
                    Kf[((size_t)nh * kS + row0 + r) * kDH + d] = (f16)(acc[mt][nt][r] + bcol);
            } else {
#pragma unroll
                for (int r = 0; r < 4; r++)
                    Qf[((size_t)nh * kS + row0 + r) * kDH + d] =
                        (f16)((acc[mt][nt][r] + bcol) * kQScale);
            }
        }
    }
}

// ---------------------------------------------------------------------------
// attn v3: 4 waves/block share K/V tiles via LDS (streamed once per block,
// not once per wave: L2 traffic /4 vs r5). Block = 128 q-rows (32/wave),
// grid (18, 8, 4) = 576 blocks = 2304 waves (r5 TLP preserved).
// K staged with layout transform on the global-read side (reads stay dense
// 1KB/wave); LDS reads are linear lane*16/lane*8 (conflict-benign).
// Compute identical to r5: S^T = K·Q^T (16x16x32), exp2 in-reg, P feeds PV
// (16x16x16) directly. Epilogue (r7-verified) -> attnF in gemm_out B-frag.
// ---------------------------------------------------------------------------
__global__ __launch_bounds__(256) void attn_f16(const f16* __restrict__ Qf,
                                                const f16* __restrict__ Kf,
                                                const f16* __restrict__ Vp,
                                                f16* __restrict__ attnF) {
    int qb = blockIdx.x, h = blockIdx.y, n = blockIdx.z;
    int nh = n * 8 + h;
    int tid  = threadIdx.x;
    int wid  = tid >> 6;
    int lane = tid & 63;
    int l15  = lane & 15;
    int quad = lane >> 4;
    int sqb  = qb * 128 + wid * 32;

    __shared__ f16 KL[2][2048];   // [buf][frag-order 4x512]
    __shared__ f16 VL[2][2048];

    const f16* Qb = Qf + (size_t)nh * kS * kDH;
    const f16* Kb = Kf + (size_t)nh * kS * kDH;
    const f16* Vb = Vp + (size_t)nh * 144 * 512;

    // staging decomposition: thread -> (frag tt, target quad, target l15)
    int stt = tid >> 6, ssq = (tid >> 4) & 3, ssl = tid & 15;
    auto stage = [&](int t, int b) {
        // K: global row-major [64][32] tile -> LDS fragment order
        *(uint4*)(&KL[b][tid * 8]) =
            *(const uint4*)(Kb + (size_t)t * 2048 + (stt * 16 + ssl) * 32 + ssq * 8);
        // V: already fragment order globally -> flat copy
        *(uint4*)(&VL[b][tid * 8]) = *(const uint4*)(Vb + (size_t)t * 2048 + (size_t)tid * 8);
    };

    f16x8 qf[2];
    {
        UF8 u;
        u.u = *(const uint4*)(Qb + (size_t)(sqb + l15) * kDH + quad * 8);      qf[0] = u.v;
        u.u = *(const uint4*)(Qb + (size_t)(sqb + 16 + l15) * kDH + quad * 8); qf[1] = u.v;
    }

    f32x4 oacc[2][2] = {};     // [dt][sqf]: O^T[d=dt*16+quad*4+r][sq=sqf*16+l15]
    float lsum[2] = {0.f, 0.f};

    stage(0, 0);
    for (int it = 0; it < 36; it++) {
        int cur = it & 1;
        __syncthreads();
        if (it < 35) stage(it + 1, cur ^ 1);

        // K/V fragments from LDS (linear addresses)
        f16x8 kfr[4];
#pragma unroll
        for (int tt = 0; tt < 4; tt++) {
            UF8 u; u.u = *(const uint4*)(&KL[cur][tt * 512 + lane * 8]);
            kfr[tt] = u.v;
        }
        f16x4 vfr[4][2];
#pragma unroll
        for (int kk = 0; kk < 4; kk++)
#pragma unroll
            for (int dt = 0; dt < 2; dt++) {
                UF4 u; u.u = *(const uint2*)(&VL[cur][kk * 512 + dt * 256 + lane * 4]);
                vfr[kk][dt] = u.v;
            }

        // logits (transposed) + exp2 + pack, in-register
        f16x4 pf[2][4];      // pf[sqf][tt]: P^T[t=tt*16+quad*4+r][sq=l15]
#pragma unroll
        for (int sqf = 0; sqf < 2; sqf++)
#pragma unroll
            for (int tt = 0; tt < 4; tt++) {
                f32x4 z = {};
                z = __builtin_amdgcn_mfma_f32_16x16x32_f16(kfr[tt], qf[sqf], z, 0, 0, 0);
                float e0 = EXP2(z[0]), e1 = EXP2(z[1]);
                float e2 = EXP2(z[2]), e3 = EXP2(z[3]);
                lsum[sqf] += (e0 + e1) + (e2 + e3);
                UF4 w;
                w.u.x = pk2(e0, e1);
                w.u.y = pk2(e2, e3);
                pf[sqf][tt] = w.v;
            }

        // PV: O^T += V^T · P^T
#pragma unroll
        for (int kk = 0; kk < 4; kk++)
#pragma unroll
            for (int dt = 0; dt < 2; dt++)
#pragma unroll
                for (int sqf = 0; sqf < 2; sqf++)
                    oacc[dt][sqf] = __builtin_amdgcn_mfma_f32_16x16x16f16(
                        vfr[kk][dt], pf[sqf][kk], oacc[dt][sqf], 0, 0, 0);
    }

#pragma unroll
    for (int sqf = 0; sqf < 2; sqf++) {
        float v = lsum[sqf];
        v += __shfl_xor(v, 16);
        v += __shfl_xor(v, 32);
        lsum[sqf] = v;
    }

    // epilogue: normalize; write attnF in gemm_out B-frag order (r7-verified):
    //   lane holds dv_local = dt*16+quad*4+r, s = sqf*16+l15 -> one 8B store.
#pragma unroll
    for (int sqf = 0; sqf < 2; sqf++) {
        float inv = 1.0f / lsum[sqf];
        int stile = qb * 8 + wid * 2 + sqf;
#pragma unroll
        for (int dt = 0; dt < 2; dt++) {
            UF4 w;
#pragma unroll
            for (int r = 0; r < 4; r++) w.v[r] = (f16)(oacc[dt][sqf][r] * inv);
            size_t off = (((size_t)(n * 144 + stile) * 8 + h) * 512)
                         + ((dt * 2 + (quad >> 1)) * 16 + l15) * 8 + (quad & 1) * 4;
            *(uint2*)(attnF + off) = w.u;
        }
    }
}

// ---------------------------------------------------------------------------
// gemm_out: LDS-free, fragment-direct, r5-style double buffer (r7-verified).
// Wave computes 32o x 64s (2x4 frags), K=256 in 8 ktiles. Grid (8,36,4).
// ---------------------------------------------------------------------------
__global__ __launch_bounds__(64) void gemm_out(const f16* __restrict__ wp,
                                               const f16* __restrict__ attnF,
                                               const float* __restrict__ bias,
                                               float* __restrict__ out) {
    int ob = blockIdx.x, sb = blockIdx.y, n = blockIdx.z;
    int lane = threadIdx.x;
    int l15  = lane & 15;
    int quad = lane >> 4;

    const f16* ap = wp + ((size_t)(ob * 2) * 8) * 512 + (size_t)lane * 8;
    const f16* bp = attnF + ((size_t)(n * 144 + sb * 4) * 8) * 512 + (size_t)lane * 8;

    f16x8 af[2], bf[4], naf[2], nbf[4];
    {
        UF8 u;
#pragma unroll
        for (int i = 0; i < 2; i++) { u.u = *(const uint4*)(ap + (i * 8) * 512); af[i] = u.v; }
#pragma unroll
        for (int i = 0; i < 4; i++) { u.u = *(const uint4*)(bp + (i * 8) * 512); bf[i] = u.v; }
    }

    f32x4 acc[2][4] = {};
#pragma unroll
    for (int kt = 0; kt < 8; kt++) {
        if (kt < 7) {
            UF8 u;
#pragma unroll
            for (int i = 0; i < 2; i++) { u.u = *(const uint4*)(ap + (i * 8 + kt + 1) * 512); naf[i] = u.v; }
#pragma unroll
            for (int i = 0; i < 4; i++) { u.u = *(const uint4*)(bp + (i * 8 + kt + 1) * 512); nbf[i] = u.v; }
        }
#pragma unroll
        for (int mt = 0; mt < 2; mt++)
#pragma unroll
            for (int nt = 0; nt < 4; nt++)
                acc[mt][nt] = __builtin_amdgcn_mfma_f32_16x16x32_f16(af[mt], bf[nt],
                                                                     acc[mt][nt], 0, 0, 0);
#pragma unroll
        for (int i = 0; i < 2; i++) af[i] = naf[i];
#pragma unroll
        for (int i = 0; i < 4; i++) bf[i] = nbf[i];
    }

#pragma unroll
    for (int mt = 0; mt < 2; mt++) {
        int row0 = ob * 32 + mt * 16 + quad * 4;   // o
#pragma unroll
        for (int nt = 0; nt < 4; nt++) {
            int col = sb * 64 + nt * 16 + l15;     // s
#pragma unroll
            for (int r = 0; r < 4; r++)
                out[((size_t)n * kDV + row0 + r) * kS + col] = acc[mt][nt][r] + bias[row0 + r];
        }
    }
}

// ---------------------------------------------------------------------------
extern "C" void kernel_launch(void* const* d_in, const int* in_sizes, int n_in,
                              void* d_out, int out_size, void* d_ws, size_t ws_size,
                              hipStream_t stream) {
    const float* x      = (const float*)d_in[0];
    const float* w_qkv  = (const float*)d_in[1];
    const float* b_qkv  = (const float*)d_in[2];
    const float* w_proj = (const float*)d_in[3];
    const float* b_proj = (const float*)d_in[4];
    float* out = (float*)d_out;

    constexpr size_t kXE = (size_t)kN * kS * kC;     // 2,359,296
    unsigned short* xh = (unsigned short*)d_ws;      // A-frag bf16 hi
    unsigned short* xl = xh + kXE;                   // A-frag bf16 lo
    unsigned short* wh = xl + kXE;                   // w_qkv B-frag hi
    unsigned short* wl = wh + 196608;
    f16* wpF   = (f16*)(wl + 196608);                // w_proj A-frag f16
    f16* Qf    = wpF + 65536;                        // [32 nh][2304][32]
    f16* Kf    = Qf + kXE;
    f16* Vp    = Kf + kXE;                           // [32 nh][144][2][64][4]
    f16* attnF = Vp + kXE;                           // B-frag [n][144][8][512]

    prep_x<<<dim3(36, 8, 4), 256, 0, stream>>>(x, xh, xl);
    prep_w<<<dim3(128), 256, 0, stream>>>(w_qkv, w_proj, wh, wl, wpF);

    gemm_qkv<<<dim3(6, 36, 4), 256, 0, stream>>>(xh, xl, wh, wl, b_qkv, Qf, Kf, Vp);

    attn_f16<<<dim3(18, 8, 4), 256, 0, stream>>>(Qf, Kf, Vp, attnF);

    gemm_out<<<dim3(8, 36, 4), 64, 0, stream>>>(wpF, attnF, b_proj, out);
}

// Round 9
// 138.906 us; speedup vs baseline: 1.4756x; 1.1001x over previous
//
#include <hip/hip_runtime.h>
#include <cstdint>

// Problem constants
constexpr int kN   = 4;
constexpr int kC   = 256;
constexpr int kS   = 2304;   // 48*48
constexpr int kDK  = 256;
constexpr int kDV  = 256;
constexpr int kDH  = 32;     // head dim
constexpr int kO   = 768;    // 2*DK + DV

typedef __bf16    bf16x8 __attribute__((ext_vector_type(8)));
typedef float     f32x4  __attribute__((ext_vector_type(4)));
typedef _Float16  f16;
typedef _Float16  f16x4  __attribute__((ext_vector_type(4)));
typedef _Float16  f16x8  __attribute__((ext_vector_type(8)));

union U4  { uint4 u; bf16x8 v; unsigned short s[8]; };
union F4  { float4 f; float a[4]; };
union UF8 { uint4 u; f16x8 v; f16 h[8]; };
union UF4 { uint2 u; f16x4 v; ushort4 su; };

#if __has_builtin(__builtin_amdgcn_exp2f)
#define EXP2(x) __builtin_amdgcn_exp2f(x)
#else
#define EXP2(x) exp2f(x)
#endif

__device__ inline float bf2f(unsigned short h) {
    unsigned int u = ((unsigned int)h) << 16;
    return __builtin_bit_cast(float, u);
}
__device__ inline unsigned short f2bf(float f) {
    unsigned int u = __builtin_bit_cast(unsigned int, f);
    u += 0x7fff + ((u >> 16) & 1);   // RNE
    return (unsigned short)(u >> 16);
}
__device__ inline void split2(float v, unsigned short& h, unsigned short& l) {
    h = f2bf(v);
    l = f2bf(v - bf2f(h));
}
__device__ inline unsigned int pk2(float a, float b) {
    auto p = __builtin_amdgcn_cvt_pkrtz(a, b);
    return __builtin_bit_cast(unsigned int, p);
}

// Fragment layouts (16x16x32 MFMA, correctness-verified rounds 6-8):
//   A/B-frag elem (row, k): lane = ((k>>3)&3)*16 + (row&15), j = k&7
//   stored [tile_row][ktile][lane 64][8]; each fragment = 512 elems contiguous.
//   C-layout: D[row = (lane>>4)*4 + reg][col = lane&15].

// ---------------------------------------------------------------------------
// prep_all: fused prep_x + prep_w (block-id split; one launch instead of two)
//   blocks [0,1152): x[n][c][s] fp32 -> split-bf16 A-frag xh/xl
//   blocks [1152,1280): w_qkv -> split-bf16 B-frag wh/wl; w_proj -> f16 A-frag
// ---------------------------------------------------------------------------
__global__ __launch_bounds__(256) void prep_all(const float* __restrict__ x,
                                                const float* __restrict__ w_qkv,
                                                const float* __restrict__ w_proj,
                                                unsigned short* __restrict__ xh,
                                                unsigned short* __restrict__ xl,
                                                unsigned short* __restrict__ wh,
                                                unsigned short* __restrict__ wl,
                                                f16* __restrict__ wp) {
    __shared__ float t[32][65];
    int b   = blockIdx.x;
    int tid = threadIdx.x;
    if (b < 1152) {
        int sblk = b % 36, cblk = (b / 36) & 7, n = b / 288;
        const float* xb = x + (size_t)n * kC * kS + (size_t)cblk * 32 * kS + (size_t)sblk * 64;
        {
            int cr = tid >> 3, sg = (tid & 7) * 8;
            F4 a0, a1;
            a0.f = *(const float4*)(xb + (size_t)cr * kS + sg);
            a1.f = *(const float4*)(xb + (size_t)cr * kS + sg + 4);
#pragma unroll
            for (int j = 0; j < 4; j++) t[cr][sg + j] = a0.a[j];
#pragma unroll
            for (int j = 0; j < 4; j++) t[cr][sg + 4 + j] = a1.a[j];
        }
        __syncthreads();
        {
            int s_loc = tid & 63, cg = tid >> 6;
            int s_g   = sblk * 64 + s_loc;
            U4 hv, lv;
#pragma unroll
            for (int j = 0; j < 8; j++) split2(t[cg * 8 + j][s_loc], hv.s[j], lv.s[j]);
            size_t frag = ((size_t)(n * 144 + (s_g >> 4)) * 8 + cblk) * 512
                          + (cg * 16 + (s_g & 15)) * 8;
            *(uint4*)(xh + frag) = hv.u;
            *(uint4*)(xl + frag) = lv.u;
        }
    } else {
        int idx = (b - 1152) * 256 + tid;
        if (idx < 24576) {           // w_qkv: 768 o x 32 c-groups
            int o = idx >> 5, cg = idx & 31;
            F4 a0, a1;
            a0.f = *(const float4*)(w_qkv + (size_t)o * kC + cg * 8);
            a1.f = *(const float4*)(w_qkv + (size_t)o * kC + cg * 8 + 4);
            U4 hv, lv;
#pragma unroll
            for (int j = 0; j < 4; j++) split2(a0.a[j], hv.s[j], lv.s[j]);
#pragma unroll
            for (int j = 0; j < 4; j++) split2(a1.a[j], hv.s[j + 4], lv.s[j + 4]);
            size_t frag = ((size_t)(o >> 4) * 8 + (cg >> 2)) * 512 + ((cg & 3) * 16 + (o & 15)) * 8;
            *(uint4*)(wh + frag) = hv.u;
            *(uint4*)(wl + frag) = lv.u;
        } else {                     // w_proj: 256 o x 32 dv-groups
            int i2 = idx - 24576;
            int o = i2 >> 5, cg = i2 & 31;
            F4 a0, a1;
            a0.f = *(const float4*)(w_proj + (size_t)o * kDV + cg * 8);
            a1.f = *(const float4*)(w_proj + (size_t)o * kDV + cg * 8 + 4);
            UF8 w;
#pragma unroll
            for (int j = 0; j < 4; j++) w.h[j] = (f16)a0.a[j];
#pragma unroll
            for (int j = 0; j < 4; j++) w.h[j + 4] = (f16)a1.a[j];
            size_t frag = ((size_t)(o >> 4) * 8 + (cg >> 2)) * 512 + ((cg & 3) * 16 + (o & 15)) * 8;
            *(uint4*)(wp + frag) = w.u;
        }
    }
}

// ---------------------------------------------------------------------------
// gemm_qkv (r8-verified structure): 4 waves/block share the A-tile via LDS;
// B frags direct from global. Block = 64s x 128o; wave 64s x 32o, K=256 in
// 8 ktiles, LDS double-buffered. Grid reordered to (sb=36, ob=6, n=4) so the
// 6 same-A blocks land on ~2 XCDs (ids differ by 36 -> %8 = +4) not 6.
// ---------------------------------------------------------------------------
__global__ __launch_bounds__(256) void gemm_qkv(const unsigned short* __restrict__ xh,
                                                const unsigned short* __restrict__ xl,
                                                const unsigned short* __restrict__ wh,
                                                const unsigned short* __restrict__ wl,
                                                const float* __restrict__ bias,
                                                f16* __restrict__ Qf,
                                                f16* __restrict__ Kf,
                                                f16* __restrict__ Vp) {
    int sb = blockIdx.x, ob = blockIdx.y, n = blockIdx.z;
    int tid  = threadIdx.x;
    int wid  = tid >> 6;
    int lane = tid & 63;
    int l15  = lane & 15;
    int quad = lane >> 4;

    __shared__ unsigned short AH[2][2048];   // [buf][mt 4][lane 64][8]
    __shared__ unsigned short AL[2][2048];

    const unsigned short* ahb = xh + ((size_t)(n * 144 + sb * 4) * 8) * 512;
    const unsigned short* alb = xl + ((size_t)(n * 144 + sb * 4) * 8) * 512;
    const unsigned short* bhb = wh + ((size_t)(ob * 8 + wid * 2) * 8) * 512 + (size_t)lane * 8;
    const unsigned short* blb = wl + ((size_t)(ob * 8 + wid * 2) * 8) * 512 + (size_t)lane * 8;

    int smt = tid >> 6, sln = tid & 63;      // staging: thread -> (frag, lane)
    auto stageA = [&](int kt, int b) {
        *(uint4*)(&AH[b][tid * 8]) = *(const uint4*)(ahb + (size_t)(smt * 8 + kt) * 512 + sln * 8);
        *(uint4*)(&AL[b][tid * 8]) = *(const uint4*)(alb + (size_t)(smt * 8 + kt) * 512 + sln * 8);
    };

    f32x4 acc[4][2] = {};
    stageA(0, 0);
#pragma unroll
    for (int kt = 0; kt < 8; kt++) {
        int cur = kt & 1;
        __syncthreads();
        if (kt < 7) stageA(kt + 1, cur ^ 1);

        bf16x8 Bh[2], Bl[2];
#pragma unroll
        for (int nt = 0; nt < 2; nt++) {
            U4 u;
            u.u = *(const uint4*)(bhb + (size_t)(nt * 8 + kt) * 512); Bh[nt] = u.v;
            u.u = *(const uint4*)(blb + (size_t)(nt * 8 + kt) * 512); Bl[nt] = u.v;
        }
        bf16x8 Ah[4], Al[4];
#pragma unroll
        for (int mt = 0; mt < 4; mt++) {
            U4 u;
            u.u = *(const uint4*)(&AH[cur][mt * 512 + lane * 8]); Ah[mt] = u.v;
            u.u = *(const uint4*)(&AL[cur][mt * 512 + lane * 8]); Al[mt] = u.v;
        }
#pragma unroll
        for (int mt = 0; mt < 4; mt++)
#pragma unroll
            for (int nt = 0; nt < 2; nt++) {
                acc[mt][nt] = __builtin_amdgcn_mfma_f32_16x16x32_bf16(Ah[mt], Bh[nt], acc[mt][nt], 0, 0, 0);
                acc[mt][nt] = __builtin_amdgcn_mfma_f32_16x16x32_bf16(Ah[mt], Bl[nt], acc[mt][nt], 0, 0, 0);
                acc[mt][nt] = __builtin_amdgcn_mfma_f32_16x16x32_bf16(Al[mt], Bh[nt], acc[mt][nt], 0, 0, 0);
            }
    }

    // Epilogue (r7-verified): D[row=s][col=o], row = quad*4+r, col = l15.
    constexpr float kQScale = 0.0625f * 1.4426950408889634f;
#pragma unroll
    for (int nt = 0; nt < 2; nt++) {
        int col = ob * 128 + wid * 32 + nt * 16 + l15;
        float bcol = bias[col];
        int sec = col >> 8;          // 0=K, 1=Q, 2=V
        int h   = (col >> 5) & 7;
        int d   = col & 31;
        int nh  = n * 8 + h;
#pragma unroll
        for (int mt = 0; mt < 4; mt++) {
            int row0 = sb * 64 + mt * 16 + quad * 4;
            if (sec == 2) {
                UF4 w;
#pragma unroll
                for (int r = 0; r < 4; r++) w.v[r] = (f16)(acc[mt][nt][r] + bcol);
                int dt = (col >> 4) & 1;
                size_t off = ((((size_t)nh * 144 + (row0 >> 4)) * 2 + dt) * 64 + lane) * 4;
                *(ushort4*)(Vp + off) = w.su;
            } else if (sec == 0) {
#pragma unroll
                for (int r = 0; r < 4; r++)
                    Kf[((size_t)nh * kS + row0 + r) * kDH + d] = (f16)(acc[mt][nt][r] + bcol);
            } else {
#pragma unroll
                for (int r = 0; r < 4; r++)
                    Qf[((size_t)nh * kS + row0 + r) * kDH + d] =
                        (f16)((acc[mt][nt][r] + bcol) * kQScale);
            }
        }
    }
}

// ---------------------------------------------------------------------------
// attn v4: r5-proven shape (single-wave blocks, LDS-free, distance-1 named
// register prefetch) + explicit VALU/MFMA interleave (PV(tt) overlaps
// exp(tt+1)) + XCD head pinning: grid (h=8, qw=72, n=4) -> linear id % 8 == h,
// so each head's K/V stream stays in one XCD's L2 (1.2 MB working set).
// Grid 2304 single-wave blocks = 9 waves/CU.
// ---------------------------------------------------------------------------
#define EXPPACK(tt)                                                         \
    {                                                                       \
        _Pragma("unroll")                                                   \
        for (int sqf = 0; sqf < 2; sqf++) {                                 \
            float e0 = EXP2(z[sqf][tt][0]), e1 = EXP2(z[sqf][tt][1]);       \
            float e2 = EXP2(z[sqf][tt][2]), e3 = EXP2(z[sqf][tt][3]);       \
            lsum[sqf] += (e0 + e1) + (e2 + e3);                             \
            UF4 w; w.u.x = pk2(e0, e1); w.u.y = pk2(e2, e3);                \
            pf[sqf][tt] = w.v;                                              \
        }                                                                   \
    }

#define PVSTEP(tt)                                                          \
    {                                                                       \
        _Pragma("unroll")                                                   \
        for (int dt = 0; dt < 2; dt++)                                      \
            _Pragma("unroll")                                               \
            for (int sqf = 0; sqf < 2; sqf++)                               \
                oacc[dt][sqf] = __builtin_amdgcn_mfma_f32_16x16x16f16(      \
                    vfr[tt][dt], pf[sqf][tt], oacc[dt][sqf], 0, 0, 0);      \
    }

__global__ __launch_bounds__(64) void attn_f16(const f16* __restrict__ Qf,
                                               const f16* __restrict__ Kf,
                                               const f16* __restrict__ Vp,
                                               f16* __restrict__ attnF) {
    int h = blockIdx.x, qw = blockIdx.y, n = blockIdx.z;
    int nh = n * 8 + h;
    int lane = threadIdx.x;
    int l15  = lane & 15;
    int quad = lane >> 4;
    int sqb  = qw * 32;

    const f16* Qb = Qf + (size_t)nh * kS * kDH;
    const f16* kp = Kf + (size_t)nh * kS * kDH + l15 * kDH + quad * 8;
    const f16* vp = Vp + (size_t)nh * 144 * 512 + lane * 4;

    f16x8 qf[2];
    {
        UF8 u;
        u.u = *(const uint4*)(Qb + (size_t)(sqb + l15) * kDH + quad * 8);      qf[0] = u.v;
        u.u = *(const uint4*)(Qb + (size_t)(sqb + 16 + l15) * kDH + quad * 8); qf[1] = u.v;
    }

    f32x4 oacc[2][2] = {};     // [dt][sqf]: O^T[d=dt*16+quad*4+r][sq=sqf*16+l15]
    float lsum[2] = {0.f, 0.f};

    f16x8 kfr[4];
    f16x4 vfr[4][2];
#pragma unroll
    for (int tt = 0; tt < 4; tt++) {
        UF8 u; u.u = *(const uint4*)(kp + tt * 512); kfr[tt] = u.v;
    }
#pragma unroll
    for (int kk = 0; kk < 4; kk++)
#pragma unroll
        for (int dt = 0; dt < 2; dt++) {
            UF4 u; u.u = *(const uint2*)(vp + kk * 512 + dt * 256); vfr[kk][dt] = u.v;
        }

    for (int t0 = 0; t0 < kS; t0 += 64) {
        // prefetch next t-tile (final iter over-reads into adjacent ws buffers)
        f16x8 kn[4];
        f16x4 vn[4][2];
#pragma unroll
        for (int tt = 0; tt < 4; tt++) {
            UF8 u; u.u = *(const uint4*)(kp + 2048 + tt * 512); kn[tt] = u.v;
        }
#pragma unroll
        for (int kk = 0; kk < 4; kk++)
#pragma unroll
            for (int dt = 0; dt < 2; dt++) {
                UF4 u; u.u = *(const uint2*)(vp + 2048 + kk * 512 + dt * 256); vn[kk][dt] = u.v;
            }

        // all QK MFMAs first (independent)
        f32x4 z[2][4];
#pragma unroll
        for (int sqf = 0; sqf < 2; sqf++)
#pragma unroll
            for (int tt = 0; tt < 4; tt++) {
                f32x4 c = {};
                z[sqf][tt] = __builtin_amdgcn_mfma_f32_16x16x32_f16(kfr[tt], qf[sqf], c, 0, 0, 0);
            }

        // interleave: PV(tt) MFMAs overlap exp/pack(tt+1) VALU
        f16x4 pf[2][4];
        EXPPACK(0)
        PVSTEP(0) EXPPACK(1)
        PVSTEP(1) EXPPACK(2)
        PVSTEP(2) EXPPACK(3)
        PVSTEP(3)

#pragma unroll
        for (int tt = 0; tt < 4; tt++) kfr[tt] = kn[tt];
#pragma unroll
        for (int kk = 0; kk < 4; kk++) {
            vfr[kk][0] = vn[kk][0];
            vfr[kk][1] = vn[kk][1];
        }
        kp += 2048;
        vp += 2048;
    }

#pragma unroll
    for (int sqf = 0; sqf < 2; sqf++) {
        float v = lsum[sqf];
        v += __shfl_xor(v, 16);
        v += __shfl_xor(v, 32);
        lsum[sqf] = v;
    }

    // epilogue: normalize; write attnF in gemm_out B-frag order (r7-verified):
    //   lane holds dv_local = dt*16+quad*4+r, s = sqf*16+l15 -> one 8B store.
#pragma unroll
    for (int sqf = 0; sqf < 2; sqf++) {
        float inv = 1.0f / lsum[sqf];
        int stile = qw * 2 + sqf;
#pragma unroll
        for (int dt = 0; dt < 2; dt++) {
            UF4 w;
#pragma unroll
            for (int r = 0; r < 4; r++) w.v[r] = (f16)(oacc[dt][sqf][r] * inv);
            size_t off = (((size_t)(n * 144 + stile) * 8 + h) * 512)
                         + ((dt * 2 + (quad >> 1)) * 16 + l15) * 8 + (quad & 1) * 4;
            *(uint2*)(attnF + off) = w.u;
        }
    }
}

// ---------------------------------------------------------------------------
// gemm_out (r7/r8-verified): LDS-free, fragment-direct, double buffer.
// Wave computes 32o x 64s (2x4 frags), K=256 in 8 ktiles. Grid (8,36,4).
// ---------------------------------------------------------------------------
__global__ __launch_bounds__(64) void gemm_out(const f16* __restrict__ wp,
                                               const f16* __restrict__ attnF,
                                               const float* __restrict__ bias,
                                               float* __restrict__ out) {
    int ob = blockIdx.x, sb = blockIdx.y, n = blockIdx.z;
    int lane = threadIdx.x;
    int l15  = lane & 15;
    int quad = lane >> 4;

    const f16* ap = wp + ((size_t)(ob * 2) * 8) * 512 + (size_t)lane * 8;
    const f16* bp = attnF + ((size_t)(n * 144 + sb * 4) * 8) * 512 + (size_t)lane * 8;

    f16x8 af[2], bf[4], naf[2], nbf[4];
    {
        UF8 u;
#pragma unroll
        for (int i = 0; i < 2; i++) { u.u = *(const uint4*)(ap + (i * 8) * 512); af[i] = u.v; }
#pragma unroll
        for (int i = 0; i < 4; i++) { u.u = *(const uint4*)(bp + (i * 8) * 512); bf[i] = u.v; }
    }

    f32x4 acc[2][4] = {};
#pragma unroll
    for (int kt = 0; kt < 8; kt++) {
        if (kt < 7) {
            UF8 u;
#pragma unroll
            for (int i = 0; i < 2; i++) { u.u = *(const uint4*)(ap + (i * 8 + kt + 1) * 512); naf[i] = u.v; }
#pragma unroll
            for (int i = 0; i < 4; i++) { u.u = *(const uint4*)(bp + (i * 8 + kt + 1) * 512); nbf[i] = u.v; }
        }
#pragma unroll
        for (int mt = 0; mt < 2; mt++)
#pragma unroll
            for (int nt = 0; nt < 4; nt++)
                acc[mt][nt] = __builtin_amdgcn_mfma_f32_16x16x32_f16(af[mt], bf[nt],
                                                                     acc[mt][nt], 0, 0, 0);
#pragma unroll
        for (int i = 0; i < 2; i++) af[i] = naf[i];
#pragma unroll
        for (int i = 0; i < 4; i++) bf[i] = nbf[i];
    }

#pragma unroll
    for (int mt = 0; mt < 2; mt++) {
        int row0 = ob * 32 + mt * 16 + quad * 4;   // o
#pragma unroll
        for (int nt = 0; nt < 4; nt++) {
            int col = sb * 64 + nt * 16 + l15;     // s
#pragma unroll
            for (int r = 0; r < 4; r++)
                out[((size_t)n * kDV + row0 + r) * kS + col] = acc[mt][nt][r] + bias[row0 + r];
        }
    }
}

// ---------------------------------------------------------------------------
extern "C" void kernel_launch(void* const* d_in, const int* in_sizes, int n_in,
                              void* d_out, int out_size, void* d_ws, size_t ws_size,
                              hipStream_t stream) {
    const float* x      = (const float*)d_in[0];
    const float* w_qkv  = (const float*)d_in[1];
    const float* b_qkv  = (const float*)d_in[2];
    const float* w_proj = (const float*)d_in[3];
    const float* b_proj = (const float*)d_in[4];
    float* out = (float*)d_out;

    constexpr size_t kXE = (size_t)kN * kS * kC;     // 2,359,296
    unsigned short* xh = (unsigned short*)d_ws;      // A-frag bf16 hi
    unsigned short* xl = xh + kXE;                   // A-frag bf16 lo
    unsigned short* wh = xl + kXE;                   // w_qkv B-frag hi
    unsigned short* wl = wh + 196608;
    f16* wpF   = (f16*)(wl + 196608);                // w_proj A-frag f16
    f16* Qf    = wpF + 65536;                        // [32 nh][2304][32]
    f16* Kf    = Qf + kXE;
    f16* Vp    = Kf + kXE;                           // [32 nh][144][2][64][4]
    f16* attnF = Vp + kXE;                           // B-frag [n][144][8][512]

    prep_all<<<dim3(1280), 256, 0, stream>>>(x, w_qkv, w_proj, xh, xl, wh, wl, wpF);

    gemm_qkv<<<dim3(36, 6, 4), 256, 0, stream>>>(xh, xl, wh, wl, b_qkv, Qf, Kf, Vp);

    attn_f16<<<dim3(8, 72, 4), 64, 0, stream>>>(Qf, Kf, Vp, attnF);

    gemm_out<<<dim3(8, 36, 4), 64, 0, stream>>>(wpF, attnF, b_proj, out);
}

// Round 10
// 138.761 us; speedup vs baseline: 1.4772x; 1.0010x over previous
//
#include <hip/hip_runtime.h>
#include <cstdint>

// Problem constants
constexpr int kN   = 4;
constexpr int kC   = 256;
constexpr int kS   = 2304;   // 48*48
constexpr int kDK  = 256;
constexpr int kDV  = 256;
constexpr int kDH  = 32;     // head dim
constexpr int kO   = 768;    // 2*DK + DV

typedef __bf16    bf16x8 __attribute__((ext_vector_type(8)));
typedef float     f32x4  __attribute__((ext_vector_type(4)));
typedef _Float16  f16;
typedef _Float16  f16x4  __attribute__((ext_vector_type(4)));
typedef _Float16  f16x8  __attribute__((ext_vector_type(8)));

union U4  { uint4 u; bf16x8 v; unsigned short s[8]; };
union F4  { float4 f; float a[4]; };
union UF8 { uint4 u; f16x8 v; f16 h[8]; };
union UF4 { uint2 u; f16x4 v; ushort4 su; };

#if __has_builtin(__builtin_amdgcn_exp2f)
#define EXP2(x) __builtin_amdgcn_exp2f(x)
#else
#define EXP2(x) exp2f(x)
#endif

__device__ inline float bf2f(unsigned short h) {
    unsigned int u = ((unsigned int)h) << 16;
    return __builtin_bit_cast(float, u);
}
__device__ inline unsigned short f2bf(float f) {
    unsigned int u = __builtin_bit_cast(unsigned int, f);
    u += 0x7fff + ((u >> 16) & 1);   // RNE
    return (unsigned short)(u >> 16);
}
__device__ inline void split2(float v, unsigned short& h, unsigned short& l) {
    h = f2bf(v);
    l = f2bf(v - bf2f(h));
}
__device__ inline unsigned int pk2(float a, float b) {
    auto p = __builtin_amdgcn_cvt_pkrtz(a, b);
    return __builtin_bit_cast(unsigned int, p);
}

// Fragment layouts (16x16x32 MFMA, correctness-verified rounds 6-9):
//   A/B-frag elem (row, k): lane = ((k>>3)&3)*16 + (row&15), j = k&7
//   stored [tile_row][ktile][lane 64][8]; each fragment = 512 elems contiguous.
//   C-layout: D[row = (lane>>4)*4 + reg][col = lane&15].

// ---------------------------------------------------------------------------
// prep_all (r9-verified): fused prep_x + prep_w
// ---------------------------------------------------------------------------
__global__ __launch_bounds__(256) void prep_all(const float* __restrict__ x,
                                                const float* __restrict__ w_qkv,
                                                const float* __restrict__ w_proj,
                                                unsigned short* __restrict__ xh,
                                                unsigned short* __restrict__ xl,
                                                unsigned short* __restrict__ wh,
                                                unsigned short* __restrict__ wl,
                                                f16* __restrict__ wp) {
    __shared__ float t[32][65];
    int b   = blockIdx.x;
    int tid = threadIdx.x;
    if (b < 1152) {
        int sblk = b % 36, cblk = (b / 36) & 7, n = b / 288;
        const float* xb = x + (size_t)n * kC * kS + (size_t)cblk * 32 * kS + (size_t)sblk * 64;
        {
            int cr = tid >> 3, sg = (tid & 7) * 8;
            F4 a0, a1;
            a0.f = *(const float4*)(xb + (size_t)cr * kS + sg);
            a1.f = *(const float4*)(xb + (size_t)cr * kS + sg + 4);
#pragma unroll
            for (int j = 0; j < 4; j++) t[cr][sg + j] = a0.a[j];
#pragma unroll
            for (int j = 0; j < 4; j++) t[cr][sg + 4 + j] = a1.a[j];
        }
        __syncthreads();
        {
            int s_loc = tid & 63, cg = tid >> 6;
            int s_g   = sblk * 64 + s_loc;
            U4 hv, lv;
#pragma unroll
            for (int j = 0; j < 8; j++) split2(t[cg * 8 + j][s_loc], hv.s[j], lv.s[j]);
            size_t frag = ((size_t)(n * 144 + (s_g >> 4)) * 8 + cblk) * 512
                          + (cg * 16 + (s_g & 15)) * 8;
            *(uint4*)(xh + frag) = hv.u;
            *(uint4*)(xl + frag) = lv.u;
        }
    } else {
        int idx = (b - 1152) * 256 + tid;
        if (idx < 24576) {           // w_qkv: 768 o x 32 c-groups
            int o = idx >> 5, cg = idx & 31;
            F4 a0, a1;
            a0.f = *(const float4*)(w_qkv + (size_t)o * kC + cg * 8);
            a1.f = *(const float4*)(w_qkv + (size_t)o * kC + cg * 8 + 4);
            U4 hv, lv;
#pragma unroll
            for (int j = 0; j < 4; j++) split2(a0.a[j], hv.s[j], lv.s[j]);
#pragma unroll
            for (int j = 0; j < 4; j++) split2(a1.a[j], hv.s[j + 4], lv.s[j + 4]);
            size_t frag = ((size_t)(o >> 4) * 8 + (cg >> 2)) * 512 + ((cg & 3) * 16 + (o & 15)) * 8;
            *(uint4*)(wh + frag) = hv.u;
            *(uint4*)(wl + frag) = lv.u;
        } else {                     // w_proj: 256 o x 32 dv-groups
            int i2 = idx - 24576;
            int o = i2 >> 5, cg = i2 & 31;
            F4 a0, a1;
            a0.f = *(const float4*)(w_proj + (size_t)o * kDV + cg * 8);
            a1.f = *(const float4*)(w_proj + (size_t)o * kDV + cg * 8 + 4);
            UF8 w;
#pragma unroll
            for (int j = 0; j < 4; j++) w.h[j] = (f16)a0.a[j];
#pragma unroll
            for (int j = 0; j < 4; j++) w.h[j + 4] = (f16)a1.a[j];
            size_t frag = ((size_t)(o >> 4) * 8 + (cg >> 2)) * 512 + ((cg & 3) * 16 + (o & 15)) * 8;
            *(uint4*)(wp + frag) = w.u;
        }
    }
}

// ---------------------------------------------------------------------------
// gemm_qkv (r9-verified): 4 waves/block share A-tile via LDS; B frags direct.
// Block 64s x 128o; wave 64s x 32o; K=256 in 8 ktiles. Grid (36, 6, 4).
// ---------------------------------------------------------------------------
__global__ __launch_bounds__(256) void gemm_qkv(const unsigned short* __restrict__ xh,
                                                const unsigned short* __restrict__ xl,
                                                const unsigned short* __restrict__ wh,
                                                const unsigned short* __restrict__ wl,
                                                const float* __restrict__ bias,
                                                f16* __restrict__ Qf,
                                                f16* __restrict__ Kf,
                                                f16* __restrict__ Vp) {
    int sb = blockIdx.x, ob = blockIdx.y, n = blockIdx.z;
    int tid  = threadIdx.x;
    int wid  = tid >> 6;
    int lane = tid & 63;
    int l15  = lane & 15;
    int quad = lane >> 4;

    __shared__ unsigned short AH[2][2048];   // [buf][mt 4][lane 64][8]
    __shared__ unsigned short AL[2][2048];

    const unsigned short* ahb = xh + ((size_t)(n * 144 + sb * 4) * 8) * 512;
    const unsigned short* alb = xl + ((size_t)(n * 144 + sb * 4) * 8) * 512;
    const unsigned short* bhb = wh + ((size_t)(ob * 8 + wid * 2) * 8) * 512 + (size_t)lane * 8;
    const unsigned short* blb = wl + ((size_t)(ob * 8 + wid * 2) * 8) * 512 + (size_t)lane * 8;

    int smt = tid >> 6, sln = tid & 63;      // staging: thread -> (frag, lane)
    auto stageA = [&](int kt, int b) {
        *(uint4*)(&AH[b][tid * 8]) = *(const uint4*)(ahb + (size_t)(smt * 8 + kt) * 512 + sln * 8);
        *(uint4*)(&AL[b][tid * 8]) = *(const uint4*)(alb + (size_t)(smt * 8 + kt) * 512 + sln * 8);
    };

    f32x4 acc[4][2] = {};
    stageA(0, 0);
#pragma unroll
    for (int kt = 0; kt < 8; kt++) {
        int cur = kt & 1;
        __syncthreads();
        if (kt < 7) stageA(kt + 1, cur ^ 1);

        bf16x8 Bh[2], Bl[2];
#pragma unroll
        for (int nt = 0; nt < 2; nt++) {
            U4 u;
            u.u = *(const uint4*)(bhb + (size_t)(nt * 8 + kt) * 512); Bh[nt] = u.v;
            u.u = *(const uint4*)(blb + (size_t)(nt * 8 + kt) * 512); Bl[nt] = u.v;
        }
        bf16x8 Ah[4], Al[4];
#pragma unroll
        for (int mt = 0; mt < 4; mt++) {
            U4 u;
            u.u = *(const uint4*)(&AH[cur][mt * 512 + lane * 8]); Ah[mt] = u.v;
            u.u = *(const uint4*)(&AL[cur][mt * 512 + lane * 8]); Al[mt] = u.v;
        }
#pragma unroll
        for (int mt = 0; mt < 4; mt++)
#pragma unroll
            for (int nt = 0; nt < 2; nt++) {
                acc[mt][nt] = __builtin_amdgcn_mfma_f32_16x16x32_bf16(Ah[mt], Bh[nt], acc[mt][nt], 0, 0, 0);
                acc[mt][nt] = __builtin_amdgcn_mfma_f32_16x16x32_bf16(Ah[mt], Bl[nt], acc[mt][nt], 0, 0, 0);
                acc[mt][nt] = __builtin_amdgcn_mfma_f32_16x16x32_bf16(Al[mt], Bh[nt], acc[mt][nt], 0, 0, 0);
            }
    }

    // Epilogue (r7-verified): D[row=s][col=o], row = quad*4+r, col = l15.
    constexpr float kQScale = 0.0625f * 1.4426950408889634f;
#pragma unroll
    for (int nt = 0; nt < 2; nt++) {
        int col = ob * 128 + wid * 32 + nt * 16 + l15;
        float bcol = bias[col];
        int sec = col >> 8;          // 0=K, 1=Q, 2=V
        int h   = (col >> 5) & 7;
        int d   = col & 31;
        int nh  = n * 8 + h;
#pragma unroll
        for (int mt = 0; mt < 4; mt++) {
            int row0 = sb * 64 + mt * 16 + quad * 4;
            if (sec == 2) {
                UF4 w;
#pragma unroll
                for (int r = 0; r < 4; r++) w.v[r] = (f16)(acc[mt][nt][r] + bcol);
                int dt = (col >> 4) & 1;
                size_t off = ((((size_t)nh * 144 + (row0 >> 4)) * 2 + dt) * 64 + lane) * 4;
                *(ushort4*)(Vp + off) = w.su;
            } else if (sec == 0) {
#pragma unroll
                for (int r = 0; r < 4; r++)
                    Kf[((size_t)nh * kS + row0 + r) * kDH + d] = (f16)(acc[mt][nt][r] + bcol);
            } else {
#pragma unroll
                for (int r = 0; r < 4; r++)
                    Qf[((size_t)nh * kS + row0 + r) * kDH + d] =
                        (f16)((acc[mt][nt][r] + bcol) * kQScale);
            }
        }
    }
}

// ---------------------------------------------------------------------------
// attn v5: split-t. 3 waves/block; wave w handles t-tiles [12w, 12w+12) of
// the SAME 32 q-rows (max-free softmax => partials are exactly additive:
// O = sum O_w, l = sum l_w; no rescaling). Inner body identical to r9
// (distance-1 named-register prefetch, EXPPACK/PVSTEP interleave). One LDS
// combine + single barrier at the end. Grid (8 h, 72 qw, 4 n) x 192 thr
// -> 6912 waves = 6.75 waves/SIMD (3x r9 TLP); L2 traffic unchanged.
// XCD head pinning preserved (linear id % 8 == h).
// ---------------------------------------------------------------------------
#define EXPPACK(tt)                                                         \
    {                                                                       \
        _Pragma("unroll")                                                   \
        for (int sqf = 0; sqf < 2; sqf++) {                                 \
            float e0 = EXP2(z[sqf][tt][0]), e1 = EXP2(z[sqf][tt][1]);       \
            float e2 = EXP2(z[sqf][tt][2]), e3 = EXP2(z[sqf][tt][3]);       \
            lsum[sqf] += (e0 + e1) + (e2 + e3);                             \
            UF4 w; w.u.x = pk2(e0, e1); w.u.y = pk2(e2, e3);                \
            pf[sqf][tt] = w.v;                                              \
        }                                                                   \
    }

#define PVSTEP(tt)                                                          \
    {                                                                       \
        _Pragma("unroll")                                                   \
        for (int dt = 0; dt < 2; dt++)                                      \
            _Pragma("unroll")                                               \
            for (int sqf = 0; sqf < 2; sqf++)                               \
                oacc[dt][sqf] = __builtin_amdgcn_mfma_f32_16x16x16f16(      \
                    vfr[tt][dt], pf[sqf][tt], oacc[dt][sqf], 0, 0, 0);      \
    }

__global__ __launch_bounds__(192) void attn_f16(const f16* __restrict__ Qf,
                                                const f16* __restrict__ Kf,
                                                const f16* __restrict__ Vp,
                                                f16* __restrict__ attnF) {
    int h = blockIdx.x, qw = blockIdx.y, n = blockIdx.z;
    int nh = n * 8 + h;
    int tid  = threadIdx.x;
    int wid  = tid >> 6;           // chunk 0..2
    int lane = tid & 63;
    int l15  = lane & 15;
    int quad = lane >> 4;
    int sqb  = qw * 32;

    __shared__ float Ored[2][2][2][64][4];   // [src wave-1][dt][sqf][lane][r]
    __shared__ float Lred[2][2][16];         // [src wave-1][sqf][l15]

    const f16* Qb = Qf + (size_t)nh * kS * kDH;
    const f16* kp = Kf + (size_t)nh * kS * kDH + (size_t)wid * 12 * 2048
                    + l15 * kDH + quad * 8;
    const f16* vp = Vp + (size_t)nh * 144 * 512 + (size_t)wid * 12 * 2048 + lane * 4;

    f16x8 qf[2];
    {
        UF8 u;
        u.u = *(const uint4*)(Qb + (size_t)(sqb + l15) * kDH + quad * 8);      qf[0] = u.v;
        u.u = *(const uint4*)(Qb + (size_t)(sqb + 16 + l15) * kDH + quad * 8); qf[1] = u.v;
    }

    f32x4 oacc[2][2] = {};     // [dt][sqf]: O^T[d=dt*16+quad*4+r][sq=sqf*16+l15]
    float lsum[2] = {0.f, 0.f};

    f16x8 kfr[4];
    f16x4 vfr[4][2];
#pragma unroll
    for (int tt = 0; tt < 4; tt++) {
        UF8 u; u.u = *(const uint4*)(kp + tt * 512); kfr[tt] = u.v;
    }
#pragma unroll
    for (int kk = 0; kk < 4; kk++)
#pragma unroll
        for (int dt = 0; dt < 2; dt++) {
            UF4 u; u.u = *(const uint2*)(vp + kk * 512 + dt * 256); vfr[kk][dt] = u.v;
        }

    for (int it = 0; it < 12; it++) {
        // prefetch next t-tile (tail over-reads land in adjacent ws buffers)
        f16x8 kn[4];
        f16x4 vn[4][2];
#pragma unroll
        for (int tt = 0; tt < 4; tt++) {
            UF8 u; u.u = *(const uint4*)(kp + 2048 + tt * 512); kn[tt] = u.v;
        }
#pragma unroll
        for (int kk = 0; kk < 4; kk++)
#pragma unroll
            for (int dt = 0; dt < 2; dt++) {
                UF4 u; u.u = *(const uint2*)(vp + 2048 + kk * 512 + dt * 256); vn[kk][dt] = u.v;
            }

        // all QK MFMAs first (independent)
        f32x4 z[2][4];
#pragma unroll
        for (int sqf = 0; sqf < 2; sqf++)
#pragma unroll
            for (int tt = 0; tt < 4; tt++) {
                f32x4 c = {};
                z[sqf][tt] = __builtin_amdgcn_mfma_f32_16x16x32_f16(kfr[tt], qf[sqf], c, 0, 0, 0);
            }

        // interleave: PV(tt) MFMAs overlap exp/pack(tt+1) VALU
        f16x4 pf[2][4];
        EXPPACK(0)
        PVSTEP(0) EXPPACK(1)
        PVSTEP(1) EXPPACK(2)
        PVSTEP(2) EXPPACK(3)
        PVSTEP(3)

#pragma unroll
        for (int tt = 0; tt < 4; tt++) kfr[tt] = kn[tt];
#pragma unroll
        for (int kk = 0; kk < 4; kk++) {
            vfr[kk][0] = vn[kk][0];
            vfr[kk][1] = vn[kk][1];
        }
        kp += 2048;
        vp += 2048;
    }

    // in-wave quad reduction of lsum (result replicated per l15 column)
#pragma unroll
    for (int sqf = 0; sqf < 2; sqf++) {
        float v = lsum[sqf];
        v += __shfl_xor(v, 16);
        v += __shfl_xor(v, 32);
        lsum[sqf] = v;
    }

    // cross-wave combine: waves 1,2 dump partials; wave 0 reduces + writes
    if (wid > 0) {
#pragma unroll
        for (int dt = 0; dt < 2; dt++)
#pragma unroll
            for (int sqf = 0; sqf < 2; sqf++)
                *(f32x4*)(&Ored[wid - 1][dt][sqf][lane][0]) = oacc[dt][sqf];
        if (quad == 0) {
            Lred[wid - 1][0][l15] = lsum[0];
            Lred[wid - 1][1][l15] = lsum[1];
        }
    }
    __syncthreads();
    if (wid != 0) return;

#pragma unroll
    for (int dt = 0; dt < 2; dt++)
#pragma unroll
        for (int sqf = 0; sqf < 2; sqf++) {
            oacc[dt][sqf] += *(const f32x4*)(&Ored[0][dt][sqf][lane][0]);
            oacc[dt][sqf] += *(const f32x4*)(&Ored[1][dt][sqf][lane][0]);
        }
    lsum[0] += Lred[0][0][l15] + Lred[1][0][l15];
    lsum[1] += Lred[0][1][l15] + Lred[1][1][l15];

    // epilogue (r7-verified): normalize; write attnF in gemm_out B-frag order
#pragma unroll
    for (int sqf = 0; sqf < 2; sqf++) {
        float inv = 1.0f / lsum[sqf];
        int stile = qw * 2 + sqf;
#pragma unroll
        for (int dt = 0; dt < 2; dt++) {
            UF4 w;
#pragma unroll
            for (int r = 0; r < 4; r++) w.v[r] = (f16)(oacc[dt][sqf][r] * inv);
            size_t off = (((size_t)(n * 144 + stile) * 8 + h) * 512)
                         + ((dt * 2 + (quad >> 1)) * 16 + l15) * 8 + (quad & 1) * 4;
            *(uint2*)(attnF + off) = w.u;
        }
    }
}

// ---------------------------------------------------------------------------
// gemm_out (r7/r8/r9-verified): LDS-free, fragment-direct, double buffer.
// Wave computes 32o x 64s (2x4 frags), K=256 in 8 ktiles. Grid (8,36,4).
// ---------------------------------------------------------------------------
__global__ __launch_bounds__(64) void gemm_out(const f16* __restrict__ wp,
                                               const f16* __restrict__ attnF,
                                               const float* __restrict__ bias,
                                               float* __restrict__ out) {
    int ob = blockIdx.x, sb = blockIdx.y, n = blockIdx.z;
    int lane = threadIdx.x;
    int l15  = lane & 15;
    int quad = lane >> 4;

    const f16* ap = wp + ((size_t)(ob * 2) * 8) * 512 + (size_t)lane * 8;
    const f16* bp = attnF + ((size_t)(n * 144 + sb * 4) * 8) * 512 + (size_t)lane * 8;

    f16x8 af[2], bf[4], naf[2], nbf[4];
    {
        UF8 u;
#pragma unroll
        for (int i = 0; i < 2; i++) { u.u = *(const uint4*)(ap + (i * 8) * 512); af[i] = u.v; }
#pragma unroll
        for (int i = 0; i < 4; i++) { u.u = *(const uint4*)(bp + (i * 8) * 512); bf[i] = u.v; }
    }

    f32x4 acc[2][4] = {};
#pragma unroll
    for (int kt = 0; kt < 8; kt++) {
        if (kt < 7) {
            UF8 u;
#pragma unroll
            for (int i = 0; i < 2; i++) { u.u = *(const uint4*)(ap + (i * 8 + kt + 1) * 512); naf[i] = u.v; }
#pragma unroll
            for (int i = 0; i < 4; i++) { u.u = *(const uint4*)(bp + (i * 8 + kt + 1) * 512); nbf[i] = u.v; }
        }
#pragma unroll
        for (int mt = 0; mt < 2; mt++)
#pragma unroll
            for (int nt = 0; nt < 4; nt++)
                acc[mt][nt] = __builtin_amdgcn_mfma_f32_16x16x32_f16(af[mt], bf[nt],
                                                                     acc[mt][nt], 0, 0, 0);
#pragma unroll
        for (int i = 0; i < 2; i++) af[i] = naf[i];
#pragma unroll
        for (int i = 0; i < 4; i++) bf[i] = nbf[i];
    }

#pragma unroll
    for (int mt = 0; mt < 2; mt++) {
        int row0 = ob * 32 + mt * 16 + quad * 4;   // o
#pragma unroll
        for (int nt = 0; nt < 4; nt++) {
            int col = sb * 64 + nt * 16 + l15;     // s
#pragma unroll
            for (int r = 0; r < 4; r++)
                out[((size_t)n * kDV + row0 + r) * kS + col] = acc[mt][nt][r] + bias[row0 + r];
        }
    }
}

// ---------------------------------------------------------------------------
extern "C" void kernel_launch(void* const* d_in, const int* in_sizes, int n_in,
                              void* d_out, int out_size, void* d_ws, size_t ws_size,
                              hipStream_t stream) {
    const float* x      = (const float*)d_in[0];
    const float* w_qkv  = (const float*)d_in[1];
    const float* b_qkv  = (const float*)d_in[2];
    const float* w_proj = (const float*)d_in[3];
    const float* b_proj = (const float*)d_in[4];
    float* out = (float*)d_out;

    constexpr size_t kXE = (size_t)kN * kS * kC;     // 2,359,296
    unsigned short* xh = (unsigned short*)d_ws;      // A-frag bf16 hi
    unsigned short* xl = xh + kXE;                   // A-frag bf16 lo
    unsigned short* wh = xl + kXE;                   // w_qkv B-frag hi
    unsigned short* wl = wh + 196608;
    f16* wpF   = (f16*)(wl + 196608);                // w_proj A-frag f16
    f16* Qf    = wpF + 65536;                        // [32 nh][2304][32]
    f16* Kf    = Qf + kXE;
    f16* Vp    = Kf + kXE;                           // [32 nh][144][2][64][4]
    f16* attnF = Vp + kXE;                           // B-frag [n][144][8][512]

    prep_all<<<dim3(1280), 256, 0, stream>>>(x, w_qkv, w_proj, xh, xl, wh, wl, wpF);

    gemm_qkv<<<dim3(36, 6, 4), 256, 0, stream>>>(xh, xl, wh, wl, b_qkv, Qf, Kf, Vp);

    attn_f16<<<dim3(8, 72, 4), 192, 0, stream>>>(Qf, Kf, Vp, attnF);

    gemm_out<<<dim3(8, 36, 4), 64, 0, stream>>>(wpF, attnF, b_proj, out);
}

// Round 11
// 138.375 us; speedup vs baseline: 1.4813x; 1.0028x over previous
//
#include <hip/hip_runtime.h>
#include <cstdint>

// Problem constants
constexpr int kN   = 4;
constexpr int kC   = 256;
constexpr int kS   = 2304;   // 48*48
constexpr int kDK  = 256;
constexpr int kDV  = 256;
constexpr int kDH  = 32;     // head dim
constexpr int kO   = 768;    // 2*DK + DV

typedef __bf16    bf16x8 __attribute__((ext_vector_type(8)));
typedef float     f32x4  __attribute__((ext_vector_type(4)));
typedef _Float16  f16;
typedef _Float16  f16x4  __attribute__((ext_vector_type(4)));
typedef _Float16  f16x8  __attribute__((ext_vector_type(8)));

union U4  { uint4 u; bf16x8 v; unsigned short s[8]; };
union F4  { float4 f; float a[4]; };
union UF8 { uint4 u; f16x8 v; f16 h[8]; };
union UF4 { uint2 u; f16x4 v; ushort4 su; };

#if __has_builtin(__builtin_amdgcn_exp2f)
#define EXP2(x) __builtin_amdgcn_exp2f(x)
#else
#define EXP2(x) exp2f(x)
#endif

__device__ inline float bf2f(unsigned short h) {
    unsigned int u = ((unsigned int)h) << 16;
    return __builtin_bit_cast(float, u);
}
__device__ inline unsigned short f2bf(float f) {
    unsigned int u = __builtin_bit_cast(unsigned int, f);
    u += 0x7fff + ((u >> 16) & 1);   // RNE
    return (unsigned short)(u >> 16);
}
__device__ inline void split2(float v, unsigned short& h, unsigned short& l) {
    h = f2bf(v);
    l = f2bf(v - bf2f(h));
}
__device__ inline unsigned int pk2(float a, float b) {
    auto p = __builtin_amdgcn_cvt_pkrtz(a, b);
    return __builtin_bit_cast(unsigned int, p);
}

// Fragment layouts (16x16x32 MFMA, correctness-verified rounds 6-10):
//   A/B-frag elem (row, k): lane = ((k>>3)&3)*16 + (row&15), j = k&7
//   stored [tile_row][ktile][lane 64][8]; each fragment = 512 elems contiguous.
//   C-layout: D[row = (lane>>4)*4 + reg][col = lane&15].

// ---------------------------------------------------------------------------
// prep_w (r9/r10-verified w-branch, now standalone): w_qkv -> split-bf16
// B-frag wh/wl [otile 48][kt 8][lane][8]; w_proj -> f16 A-frag wp. Grid 128.
// ---------------------------------------------------------------------------
__global__ __launch_bounds__(256) void prep_w(const float* __restrict__ w_qkv,
                                              const float* __restrict__ w_proj,
                                              unsigned short* __restrict__ wh,
                                              unsigned short* __restrict__ wl,
                                              f16* __restrict__ wp) {
    int idx = blockIdx.x * 256 + threadIdx.x;
    if (idx < 24576) {           // w_qkv: 768 o x 32 c-groups
        int o = idx >> 5, cg = idx & 31;
        F4 a0, a1;
        a0.f = *(const float4*)(w_qkv + (size_t)o * kC + cg * 8);
        a1.f = *(const float4*)(w_qkv + (size_t)o * kC + cg * 8 + 4);
        U4 hv, lv;
#pragma unroll
        for (int j = 0; j < 4; j++) split2(a0.a[j], hv.s[j], lv.s[j]);
#pragma unroll
        for (int j = 0; j < 4; j++) split2(a1.a[j], hv.s[j + 4], lv.s[j + 4]);
        size_t frag = ((size_t)(o >> 4) * 8 + (cg >> 2)) * 512 + ((cg & 3) * 16 + (o & 15)) * 8;
        *(uint4*)(wh + frag) = hv.u;
        *(uint4*)(wl + frag) = lv.u;
    } else {                     // w_proj: 256 o x 32 dv-groups
        int i2 = idx - 24576;
        int o = i2 >> 5, cg = i2 & 31;
        F4 a0, a1;
        a0.f = *(const float4*)(w_proj + (size_t)o * kDV + cg * 8);
        a1.f = *(const float4*)(w_proj + (size_t)o * kDV + cg * 8 + 4);
        UF8 w;
#pragma unroll
        for (int j = 0; j < 4; j++) w.h[j] = (f16)a0.a[j];
#pragma unroll
        for (int j = 0; j < 4; j++) w.h[j + 4] = (f16)a1.a[j];
        size_t frag = ((size_t)(o >> 4) * 8 + (cg >> 2)) * 512 + ((cg & 3) * 16 + (o & 15)) * 8;
        *(uint4*)(wp + frag) = w.u;
    }
}

// ---------------------------------------------------------------------------
// gemm_qkv (fused prep_x): block (sb, oh, n) covers 64 s x 256 o where
// oh = section (0=K, 1=Q, 2=V). Stage: each block transposes+splits its own
// x strip [64 s][256 c] into LDS in A-frag order (one barrier total), then
// an LDS-resident K-loop: per ktile 8 B-frag global loads (L2-hot w) +
// 8 ds_read_b128 + 48 MFMAs (split-bf16), no further barriers.
// Grid (36, 3, 4) = 432 blocks x 256 thr; wave = 64s x 64o (4x4 frags).
// Eliminates the xh/xl HBM round-trip + the prep_x launch.
// ---------------------------------------------------------------------------
__global__ __launch_bounds__(256) void gemm_qkv(const float* __restrict__ x,
                                                const unsigned short* __restrict__ wh,
                                                const unsigned short* __restrict__ wl,
                                                const float* __restrict__ bias,
                                                f16* __restrict__ Qf,
                                                f16* __restrict__ Kf,
                                                f16* __restrict__ Vp) {
    int sb = blockIdx.x, oh = blockIdx.y, n = blockIdx.z;
    int tid  = threadIdx.x;
    int wid  = tid >> 6;
    int lane = tid & 63;
    int l15  = lane & 15;
    int quad = lane >> 4;
    int s0   = sb * 64;

    __shared__ unsigned short AH[16384];   // [kt 8][mt 4][lane 64][8]
    __shared__ unsigned short AL[16384];

    // ---- stage x strip -> split-bf16 A-frag LDS ----
    {
        int cg = tid >> 6, sl = tid & 63;
        const float* xb = x + (size_t)n * kC * kS + s0 + sl;
#pragma unroll
        for (int r = 0; r < 8; r++) {
            U4 hv, lv;
#pragma unroll
            for (int j = 0; j < 8; j++) {
                float v = xb[(size_t)(r * 32 + cg * 8 + j) * kS];
                split2(v, hv.s[j], lv.s[j]);
            }
            int off = r * 2048 + (sl >> 4) * 512 + (cg * 16 + (sl & 15)) * 8;
            *(uint4*)(&AH[off]) = hv.u;
            *(uint4*)(&AL[off]) = lv.u;
        }
    }
    __syncthreads();

    const unsigned short* bhb = wh + ((size_t)(oh * 16 + wid * 4) * 8) * 512 + (size_t)lane * 8;
    const unsigned short* blb = wl + ((size_t)(oh * 16 + wid * 4) * 8) * 512 + (size_t)lane * 8;

    f32x4 acc[4][4] = {};
#pragma unroll
    for (int kt = 0; kt < 8; kt++) {
        bf16x8 Bh[4], Bl[4];
#pragma unroll
        for (int nt = 0; nt < 4; nt++) {
            U4 u;
            u.u = *(const uint4*)(bhb + (size_t)(nt * 8 + kt) * 512); Bh[nt] = u.v;
            u.u = *(const uint4*)(blb + (size_t)(nt * 8 + kt) * 512); Bl[nt] = u.v;
        }
        bf16x8 Ah[4], Al[4];
#pragma unroll
        for (int mt = 0; mt < 4; mt++) {
            U4 u;
            u.u = *(const uint4*)(&AH[kt * 2048 + mt * 512 + lane * 8]); Ah[mt] = u.v;
            u.u = *(const uint4*)(&AL[kt * 2048 + mt * 512 + lane * 8]); Al[mt] = u.v;
        }
#pragma unroll
        for (int mt = 0; mt < 4; mt++)
#pragma unroll
            for (int nt = 0; nt < 4; nt++) {
                acc[mt][nt] = __builtin_amdgcn_mfma_f32_16x16x32_bf16(Ah[mt], Bh[nt], acc[mt][nt], 0, 0, 0);
                acc[mt][nt] = __builtin_amdgcn_mfma_f32_16x16x32_bf16(Ah[mt], Bl[nt], acc[mt][nt], 0, 0, 0);
                acc[mt][nt] = __builtin_amdgcn_mfma_f32_16x16x32_bf16(Al[mt], Bh[nt], acc[mt][nt], 0, 0, 0);
            }
    }

    // Epilogue (r7-verified): D[row=s][col=o], row = quad*4+r, col = l15.
    constexpr float kQScale = 0.0625f * 1.4426950408889634f;
#pragma unroll
    for (int nt = 0; nt < 4; nt++) {
        int col = oh * 256 + wid * 64 + nt * 16 + l15;
        float bcol = bias[col];
        int h   = (col >> 5) & 7;
        int d   = col & 31;
        int nh  = n * 8 + h;
#pragma unroll
        for (int mt = 0; mt < 4; mt++) {
            int row0 = s0 + mt * 16 + quad * 4;
            if (oh == 2) {
                UF4 w;
#pragma unroll
                for (int r = 0; r < 4; r++) w.v[r] = (f16)(acc[mt][nt][r] + bcol);
                int dt = (col >> 4) & 1;
                size_t off = ((((size_t)nh * 144 + (row0 >> 4)) * 2 + dt) * 64 + lane) * 4;
                *(ushort4*)(Vp + off) = w.su;
            } else if (oh == 0) {
#pragma unroll
                for (int r = 0; r < 4; r++)
                    Kf[((size_t)nh * kS + row0 + r) * kDH + d] = (f16)(acc[mt][nt][r] + bcol);
            } else {
#pragma unroll
                for (int r = 0; r < 4; r++)
                    Qf[((size_t)nh * kS + row0 + r) * kDH + d] =
                        (f16)((acc[mt][nt][r] + bcol) * kQScale);
            }
        }
    }
}

// ---------------------------------------------------------------------------
// attn v6: r10 split-t structure (3 waves/block over t-chunks, max-free
// softmax => partials exactly additive; one end-of-kernel combine barrier)
// with the iteration body ping-pong-unrolled x2: two named buffer sets used
// alternately -> the ~40 v_mov/iter buffer-rotation copies are GONE.
// Grid (8 h, 72 qw, 4 n) x 192 thr; XCD head pinning (id % 8 == h).
// ---------------------------------------------------------------------------
#define EXPPACK(tt)                                                         \
    {                                                                       \
        _Pragma("unroll")                                                   \
        for (int sqf = 0; sqf < 2; sqf++) {                                 \
            float e0 = EXP2(z[sqf][tt][0]), e1 = EXP2(z[sqf][tt][1]);       \
            float e2 = EXP2(z[sqf][tt][2]), e3 = EXP2(z[sqf][tt][3]);       \
            lsum[sqf] += (e0 + e1) + (e2 + e3);                             \
            UF4 w; w.u.x = pk2(e0, e1); w.u.y = pk2(e2, e3);                \
            pf[sqf][tt] = w.v;                                              \
        }                                                                   \
    }

#define PVSTEP(VC, tt)                                                     \
    {                                                                      \
        _Pragma("unroll")                                                  \
        for (int dt = 0; dt < 2; dt++)                                     \
            _Pragma("unroll")                                              \
            for (int sqf = 0; sqf < 2; sqf++)                              \
                oacc[dt][sqf] = __builtin_amdgcn_mfma_f32_16x16x16f16(     \
                    VC[tt][dt], pf[sqf][tt], oacc[dt][sqf], 0, 0, 0);      \
    }

#define ATTN_BODY(KC, VC, KN, VN)                                          \
    {                                                                      \
        _Pragma("unroll")                                                  \
        for (int tt = 0; tt < 4; tt++) {                                   \
            UF8 u; u.u = *(const uint4*)(kp + 2048 + tt * 512);            \
            KN[tt] = u.v;                                                  \
        }                                                                  \
        _Pragma("unroll")                                                  \
        for (int kk = 0; kk < 4; kk++) {                                   \
            UF4 u;                                                         \
            u.u = *(const uint2*)(vp + 2048 + kk * 512);       VN[kk][0] = u.v; \
            u.u = *(const uint2*)(vp + 2048 + kk * 512 + 256); VN[kk][1] = u.v; \
        }                                                                  \
        f32x4 z[2][4];                                                     \
        _Pragma("unroll")                                                  \
        for (int sqf = 0; sqf < 2; sqf++)                                  \
            _Pragma("unroll")                                              \
            for (int tt = 0; tt < 4; tt++) {                               \
                f32x4 c = {};                                              \
                z[sqf][tt] = __builtin_amdgcn_mfma_f32_16x16x32_f16(       \
                    KC[tt], qf[sqf], c, 0, 0, 0);                          \
            }                                                              \
        f16x4 pf[2][4];                                                    \
        EXPPACK(0) PVSTEP(VC, 0) EXPPACK(1) PVSTEP(VC, 1)                  \
        EXPPACK(2) PVSTEP(VC, 2) EXPPACK(3) PVSTEP(VC, 3)                  \
        kp += 2048;                                                        \
        vp += 2048;                                                        \
    }

__global__ __launch_bounds__(192) void attn_f16(const f16* __restrict__ Qf,
                                                const f16* __restrict__ Kf,
                                                const f16* __restrict__ Vp,
                                                f16* __restrict__ attnF) {
    int h = blockIdx.x, qw = blockIdx.y, n = blockIdx.z;
    int nh = n * 8 + h;
    int tid  = threadIdx.x;
    int wid  = tid >> 6;           // t-chunk 0..2
    int lane = tid & 63;
    int l15  = lane & 15;
    int quad = lane >> 4;
    int sqb  = qw * 32;

    __shared__ float Ored[2][2][2][64][4];   // [src wave-1][dt][sqf][lane][r]
    __shared__ float Lred[2][2][16];         // [src wave-1][sqf][l15]

    const f16* Qb = Qf + (size_t)nh * kS * kDH;
    const f16* kp = Kf + (size_t)nh * kS * kDH + (size_t)wid * 12 * 2048
                    + l15 * kDH + quad * 8;
    const f16* vp = Vp + (size_t)nh * 144 * 512 + (size_t)wid * 12 * 2048 + lane * 4;

    f16x8 qf[2];
    {
        UF8 u;
        u.u = *(const uint4*)(Qb + (size_t)(sqb + l15) * kDH + quad * 8);      qf[0] = u.v;
        u.u = *(const uint4*)(Qb + (size_t)(sqb + 16 + l15) * kDH + quad * 8); qf[1] = u.v;
    }

    f32x4 oacc[2][2] = {};     // [dt][sqf]: O^T[d=dt*16+quad*4+r][sq=sqf*16+l15]
    float lsum[2] = {0.f, 0.f};

    f16x8 kA[4], kB[4];
    f16x4 vA[4][2], vB[4][2];
#pragma unroll
    for (int tt = 0; tt < 4; tt++) {
        UF8 u; u.u = *(const uint4*)(kp + tt * 512); kA[tt] = u.v;
    }
#pragma unroll
    for (int kk = 0; kk < 4; kk++) {
        UF4 u;
        u.u = *(const uint2*)(vp + kk * 512);       vA[kk][0] = u.v;
        u.u = *(const uint2*)(vp + kk * 512 + 256); vA[kk][1] = u.v;
    }

    // 12 t-tiles per wave, ping-pong x2 (no buffer copies); tail over-reads
    // land in the adjacent ws buffers (allocated, values unused).
    for (int it = 0; it < 6; it++) {
        ATTN_BODY(kA, vA, kB, vB)
        ATTN_BODY(kB, vB, kA, vA)
    }

    // in-wave quad reduction of lsum (result replicated per l15 column)
#pragma unroll
    for (int sqf = 0; sqf < 2; sqf++) {
        float v = lsum[sqf];
        v += __shfl_xor(v, 16);
        v += __shfl_xor(v, 32);
        lsum[sqf] = v;
    }

    // cross-wave combine: waves 1,2 dump partials; wave 0 reduces + writes
    if (wid > 0) {
#pragma unroll
        for (int dt = 0; dt < 2; dt++)
#pragma unroll
            for (int sqf = 0; sqf < 2; sqf++)
                *(f32x4*)(&Ored[wid - 1][dt][sqf][lane][0]) = oacc[dt][sqf];
        if (quad == 0) {
            Lred[wid - 1][0][l15] = lsum[0];
            Lred[wid - 1][1][l15] = lsum[1];
        }
    }
    __syncthreads();
    if (wid != 0) return;

#pragma unroll
    for (int dt = 0; dt < 2; dt++)
#pragma unroll
        for (int sqf = 0; sqf < 2; sqf++) {
            oacc[dt][sqf] += *(const f32x4*)(&Ored[0][dt][sqf][lane][0]);
            oacc[dt][sqf] += *(const f32x4*)(&Ored[1][dt][sqf][lane][0]);
        }
    lsum[0] += Lred[0][0][l15] + Lred[1][0][l15];
    lsum[1] += Lred[0][1][l15] + Lred[1][1][l15];

    // epilogue (r7-verified): normalize; write attnF in gemm_out B-frag order
#pragma unroll
    for (int sqf = 0; sqf < 2; sqf++) {
        float inv = 1.0f / lsum[sqf];
        int stile = qw * 2 + sqf;
#pragma unroll
        for (int dt = 0; dt < 2; dt++) {
            UF4 w;
#pragma unroll
            for (int r = 0; r < 4; r++) w.v[r] = (f16)(oacc[dt][sqf][r] * inv);
            size_t off = (((size_t)(n * 144 + stile) * 8 + h) * 512)
                         + ((dt * 2 + (quad >> 1)) * 16 + l15) * 8 + (quad & 1) * 4;
            *(uint2*)(attnF + off) = w.u;
        }
    }
}

// ---------------------------------------------------------------------------
// gemm_out (r7-r10-verified): LDS-free, fragment-direct, double buffer.
// Wave computes 32o x 64s (2x4 frags), K=256 in 8 ktiles. Grid (8,36,4).
// ---------------------------------------------------------------------------
__global__ __launch_bounds__(64) void gemm_out(const f16* __restrict__ wp,
                                               const f16* __restrict__ attnF,
                                               const float* __restrict__ bias,
                                               float* __restrict__ out) {
    int ob = blockIdx.x, sb = blockIdx.y, n = blockIdx.z;
    int lane = threadIdx.x;
    int l15  = lane & 15;
    int quad = lane >> 4;

    const f16* ap = wp + ((size_t)(ob * 2) * 8) * 512 + (size_t)lane * 8;
    const f16* bp = attnF + ((size_t)(n * 144 + sb * 4) * 8) * 512 + (size_t)lane * 8;

    f16x8 af[2], bf[4], naf[2], nbf[4];
    {
        UF8 u;
#pragma unroll
        for (int i = 0; i < 2; i++) { u.u = *(const uint4*)(ap + (i * 8) * 512); af[i] = u.v; }
#pragma unroll
        for (int i = 0; i < 4; i++) { u.u = *(const uint4*)(bp + (i * 8) * 512); bf[i] = u.v; }
    }

    f32x4 acc[2][4] = {};
#pragma unroll
    for (int kt = 0; kt < 8; kt++) {
        if (kt < 7) {
            UF8 u;
#pragma unroll
            for (int i = 0; i < 2; i++) { u.u = *(const uint4*)(ap + (i * 8 + kt + 1) * 512); naf[i] = u.v; }
#pragma unroll
            for (int i = 0; i < 4; i++) { u.u = *(const uint4*)(bp + (i * 8 + kt + 1) * 512); nbf[i] = u.v; }
        }
#pragma unroll
        for (int mt = 0; mt < 2; mt++)
#pragma unroll
            for (int nt = 0; nt < 4; nt++)
                acc[mt][nt] = __builtin_amdgcn_mfma_f32_16x16x32_f16(af[mt], bf[nt],
                                                                     acc[mt][nt], 0, 0, 0);
#pragma unroll
        for (int i = 0; i < 2; i++) af[i] = naf[i];
#pragma unroll
        for (int i = 0; i < 4; i++) bf[i] = nbf[i];
    }

#pragma unroll
    for (int mt = 0; mt < 2; mt++) {
        int row0 = ob * 32 + mt * 16 + quad * 4;   // o
#pragma unroll
        for (int nt = 0; nt < 4; nt++) {
            int col = sb * 64 + nt * 16 + l15;     // s
#pragma unroll
            for (int r = 0; r < 4; r++)
                out[((size_t)n * kDV + row0 + r) * kS + col] = acc[mt][nt][r] + bias[row0 + r];
        }
    }
}

// ---------------------------------------------------------------------------
extern "C" void kernel_launch(void* const* d_in, const int* in_sizes, int n_in,
                              void* d_out, int out_size, void* d_ws, size_t ws_size,
                              hipStream_t stream) {
    const float* x      = (const float*)d_in[0];
    const float* w_qkv  = (const float*)d_in[1];
    const float* b_qkv  = (const float*)d_in[2];
    const float* w_proj = (const float*)d_in[3];
    const float* b_proj = (const float*)d_in[4];
    float* out = (float*)d_out;

    constexpr size_t kXE = (size_t)kN * kS * kC;     // 2,359,296
    unsigned short* wh = (unsigned short*)d_ws;      // w_qkv B-frag hi
    unsigned short* wl = wh + 196608;
    f16* wpF   = (f16*)(wl + 196608);                // w_proj A-frag f16
    f16* Qf    = wpF + 65536;                        // [32 nh][2304][32]
    f16* Kf    = Qf + kXE;
    f16* Vp    = Kf + kXE;                           // [32 nh][144][2][64][4]
    f16* attnF = Vp + kXE;                           // B-frag [n][144][8][512]

    prep_w<<<dim3(128), 256, 0, stream>>>(w_qkv, w_proj, wh, wl, wpF);

    gemm_qkv<<<dim3(36, 3, 4), 256, 0, stream>>>(x, wh, wl, b_qkv, Qf, Kf, Vp);

    attn_f16<<<dim3(8, 72, 4), 192, 0, stream>>>(Qf, Kf, Vp, attnF);

    gemm_out<<<dim3(8, 36, 4), 64, 0, stream>>>(wpF, attnF, b_proj, out);
}